// Round 10
// baseline (731.326 us; speedup 1.0000x reference)
//
#include <hip/hip_runtime.h>

#define DEV static __device__ __forceinline__

constexpr int Bc = 2, Tc = 128, Nc = 1024, Fc = 128, Hc = 4, Rc = 32, Dc = 32;
constexpr int NF  = Nc * Fc;        // 131072 = 2^17
constexpr int TOK = Bc * Tc * Nc;   // 262144
constexpr float EPSc = 1e-6f;
constexpr float RSD  = 0.17677669529663687f;  // 1/sqrt(32)

typedef __bf16 bf16x8 __attribute__((ext_vector_type(8)));
typedef float  f32x16 __attribute__((ext_vector_type(16)));
typedef unsigned short us8 __attribute__((ext_vector_type(8)));
typedef unsigned short us4 __attribute__((ext_vector_type(4)));

DEV unsigned short f2bu(float f) {              // fp32 -> bf16 (RNE)
    unsigned u = __builtin_bit_cast(unsigned, f);
    u += 0x7fffu + ((u >> 16) & 1u);
    return (unsigned short)(u >> 16);
}
DEV float bu2f(unsigned short s) {
    return __builtin_bit_cast(float, ((unsigned)s) << 16);
}
DEV unsigned pk2(float lo, float hi) {          // 2 x f32 -> packed bf16 pair
    return (unsigned)f2bu(lo) | ((unsigned)f2bu(hi) << 16);
}
DEV float sigmoidf_(float z) { return 1.f / (1.f + __expf(-z)); }
DEV f32x16 zero16() { f32x16 z;
#pragma unroll
    for (int i = 0; i < 16; i++) z[i] = 0.f;
    return z; }

// ---------------- K1: rmsnorm-over-t scale factors (for x fp32) -----------------
__global__ void k_rms_f32(const float* __restrict__ x, float* __restrict__ inv) {
    int j = blockIdx.x * 256 + threadIdx.x;     // j = b*NF + p
    int b = j >> 17;
    int p = j & (NF - 1);
    const float* px = x + (size_t)b * Tc * NF + p;
    float s = 0.f;
#pragma unroll 8
    for (int t = 0; t < Tc; ++t) { float v = px[(size_t)t * NF]; s = fmaf(v, v, s); }
    inv[j] = rsqrtf(s * (1.f / Tc) + EPSc);
}

// ---------------- weight fp32 -> bf16 conversions (w1,w2,w3 fused) ----------------
__global__ void k_cvt3(const float* __restrict__ w1, const float* __restrict__ w2,
                       const float* __restrict__ w3, unsigned short* __restrict__ o) {
    int i = blockIdx.x * 256 + threadIdx.x;     // 196608 total
    float v;
    if (i < 65536)       v = w1[i];
    else if (i < 131072) v = w2[i - 65536];
    else                 v = w3[i - 131072];
    o[i] = f2bu(v);
}

// ---------------- K_qk: fold q_w,key_p into QK + v_w cvt + biases ----------------
__global__ void k_qk(const float* __restrict__ q_w, const float* __restrict__ q_b,
                     const float* __restrict__ key_p, const float* __restrict__ v_b,
                     const float* __restrict__ v_w,
                     unsigned short* __restrict__ Wcat, float* __restrict__ bias)
{
    int blk = blockIdx.x, tid = threadIdx.x;
    if (blk >= 4) {
        int i = (blk - 4) * 256 + tid;           // 0..16383
        Wcat[16384 + i] = f2bu(v_w[i]);
        return;
    }
    __shared__ float sqw[32][128];   // [d][c] for this h
    __shared__ float skp[32][32];    // [r][d], pre-scaled by RSD
    int h = blk;
    for (int i = tid; i < 4096; i += 256) {
        int d = i >> 7, c = i & 127;
        sqw[d][c] = q_w[(size_t)(h * 32 + d) * 128 + c];
    }
    for (int i = tid; i < 1024; i += 256) {
        int r = i >> 5, d = i & 31;
        skp[r][d] = key_p[(size_t)(r * 4 + h) * 32 + d] * RSD;
    }
    __syncthreads();
    int r = tid >> 3;
    int c0 = (tid & 7) * 16;
    for (int cc = 0; cc < 16; ++cc) {
        int c = c0 + cc;
        float s = 0.f;
#pragma unroll
        for (int d = 0; d < 32; ++d) s = fmaf(sqw[d][c], skp[r][d], s);
        Wcat[(size_t)(h * 32 + r) * 128 + c] = f2bu(s);
    }
    if (tid < 32) {
        float s = 0.f;
#pragma unroll
        for (int d = 0; d < 32; ++d) s = fmaf(q_b[h * 32 + d], skp[tid][d], s);
        bias[h * 32 + tid] = s;
    }
    if (h == 0 && tid >= 64 && tid < 192) bias[128 + tid - 64] = v_b[tid - 64];
}

// ---------------- K2: MFMA projection: [L ; XV] = XN @ Wcat^T + bias ----------------
__global__ __launch_bounds__(256, 4) void k_projm(
    const float* __restrict__ x, const float* __restrict__ inv1, const float* __restrict__ nw,
    const unsigned short* __restrict__ Wcat, const float* __restrict__ bias,
    unsigned short* __restrict__ Lb, unsigned short* __restrict__ XVb)
{
    const int tid = threadIdx.x, lane = tid & 63, wv = tid >> 6;
    const int lr = lane & 31, lhi = lane >> 5;
    const int tokb = blockIdx.x * 128 + wv * 32;
    const int tok = tokb + lr;
    const int b = tok >> 17, n = tok & 1023;
    const float* px = x + (size_t)tok * 128;
    const float* pi = inv1 + (size_t)b * NF + n * 128;

    bf16x8 af[8];
#pragma unroll
    for (int s = 0; s < 8; ++s) {
        const int c0 = s * 16 + lhi * 8;
        float4 xa = *(const float4*)(px + c0);
        float4 xb = *(const float4*)(px + c0 + 4);
        float4 ia = *(const float4*)(pi + c0);
        float4 ib = *(const float4*)(pi + c0 + 4);
        float4 na = *(const float4*)(nw + c0);
        float4 nb = *(const float4*)(nw + c0 + 4);
        bf16x8 v;
        v[0] = (__bf16)(xa.x * ia.x * na.x);
        v[1] = (__bf16)(xa.y * ia.y * na.y);
        v[2] = (__bf16)(xa.z * ia.z * na.z);
        v[3] = (__bf16)(xa.w * ia.w * na.w);
        v[4] = (__bf16)(xb.x * ib.x * nb.x);
        v[5] = (__bf16)(xb.y * ib.y * nb.y);
        v[6] = (__bf16)(xb.z * ib.z * nb.z);
        v[7] = (__bf16)(xb.w * ib.w * nb.w);
        af[s] = v;
    }

#pragma unroll
    for (int ot = 0; ot < 8; ++ot) {
        const unsigned short* pw = Wcat + (size_t)(ot * 32 + lr) * 128 + lhi * 8;
        f32x16 acc = zero16();
#pragma unroll
        for (int s = 0; s < 8; ++s) {
            bf16x8 bw = *(const bf16x8*)(pw + s * 16);
            acc = __builtin_amdgcn_mfma_f32_32x32x16_bf16(af[s], bw, acc, 0, 0, 0);
        }
        const int o = ot * 32 + lr;
        const float bv = bias[o];
        unsigned short* dst = (ot < 4) ? Lb : XVb;
        const int oo = (ot < 4) ? o : o - 128;
#pragma unroll
        for (int r = 0; r < 16; ++r) {
            const int trow = tokb + (r & 3) + 8 * (r >> 2) + 4 * lhi;
            dst[(size_t)trow * 128 + oo] = f2bu(acc[r] + bv);
        }
    }
}

// ---------------- K3: landmark aggregation + n-softmax stats (parallel, vec loads) ----------------
__global__ __launch_bounds__(256, 4) void k_land(
    const unsigned short* __restrict__ Lb, const unsigned short* __restrict__ XVb,
    float* __restrict__ VL, float* __restrict__ M2, float* __restrict__ S2)
{
    __shared__ float sL [64][34];
    __shared__ float sXV[64][36];
    __shared__ float redm[32][8];
    __shared__ float reds[32][8];
    int tid = threadIdx.x;
    int blk = blockIdx.x;               // bt*4 + h
    int h = blk & 3; int bt = blk >> 2;
    size_t base = (size_t)bt * Nc * 128 + h * 32;
    const int li = tid >> 2, c8 = (tid & 3) * 8;      // load mapping (us8)
    const int r_st = tid & 31, stripe = tid >> 5;     // stats mapping
    const int ti = tid >> 2, sub = tid & 3;           // p1 mapping
    const int r_acc = tid >> 3, d0 = (tid & 7) * 4;   // VL mapping
    float m_st = -1e30f, s_st = 0.f;
    float a0 = 0, a1 = 0, a2 = 0, a3 = 0;
    for (int n0 = 0; n0 < Nc; n0 += 64) {
        {
            size_t g = base + (size_t)(n0 + li) * 128 + c8;
            us8 vL = *(const us8*)(Lb + g);
            us8 vX = *(const us8*)(XVb + g);
#pragma unroll
            for (int j = 0; j < 8; ++j) {
                sL [li][c8 + j] = bu2f(vL[j]);
                sXV[li][c8 + j] = bu2f(vX[j]);
            }
        }
        __syncthreads();
        // ---- online n-softmax stats: thread = (r, 8-token stripe) ----
#pragma unroll
        for (int i8 = 0; i8 < 8; ++i8) {
            float v = sL[stripe * 8 + i8][r_st];
            float mn = fmaxf(m_st, v);
            s_st = s_st * __expf(m_st - mn) + __expf(v - mn);
            m_st = mn;
        }
        // ---- p1 softmax over r: 4 threads per token, 8 r each ----
        float e[8];
        float mx = -1e30f;
#pragma unroll
        for (int j = 0; j < 8; ++j) mx = fmaxf(mx, sL[ti][sub * 8 + j]);
        mx = fmaxf(mx, __shfl_xor(mx, 1));
        mx = fmaxf(mx, __shfl_xor(mx, 2));
        float sm = 0.f;
#pragma unroll
        for (int j = 0; j < 8; ++j) { e[j] = __expf(sL[ti][sub * 8 + j] - mx); sm += e[j]; }
        sm += __shfl_xor(sm, 1);
        sm += __shfl_xor(sm, 2);
        float iv = 1.f / sm;
        __syncthreads();                 // all reads of sL done
#pragma unroll
        for (int j = 0; j < 8; ++j) sL[ti][sub * 8 + j] = e[j] * iv;
        __syncthreads();
        // ---- VL accumulate: thread = (r, 4 d) ----
#pragma unroll 2
        for (int i = 0; i < 64; ++i) {
            float p = sL[i][r_acc];
            float4 v = *(const float4*)&sXV[i][d0];
            a0 = fmaf(p, v.x, a0); a1 = fmaf(p, v.y, a1);
            a2 = fmaf(p, v.z, a2); a3 = fmaf(p, v.w, a3);
        }
        __syncthreads();
    }
    redm[r_st][stripe] = m_st;
    reds[r_st][stripe] = s_st;
    __syncthreads();
    if (tid < 32) {
        float m = -1e30f;
#pragma unroll
        for (int k = 0; k < 8; ++k) m = fmaxf(m, redm[tid][k]);
        float s = 0.f;
#pragma unroll
        for (int k = 0; k < 8; ++k) s += reds[tid][k] * __expf(redm[tid][k] - m);
        M2[blk * 32 + tid] = m;
        S2[blk * 32 + tid] = s;
    }
    *(float4*)&VL[((size_t)blk * 32 + r_acc) * 32 + d0] = make_float4(a0, a1, a2, a3);
}

// ---------------- K4: scatter landmarks + gates + first residual ----------------
__global__ void k_out1(const float* __restrict__ x,
                       const unsigned short* __restrict__ Lb, const unsigned short* __restrict__ XVb,
                       const float* __restrict__ VL, const float* __restrict__ M2, const float* __restrict__ S2,
                       const float* __restrict__ alpha, const float* __restrict__ beta,
                       unsigned short* __restrict__ X2b)
{
    __shared__ float sVL[128][32];
    __shared__ float sP[8][128];
    __shared__ float sM[128], sSi[128], sAB[8];
    int tid = threadIdx.x;
    int tk0 = blockIdx.x * 8;
    int bt = tk0 >> 10;
    for (int k = tid; k < 4096; k += 256) sVL[k >> 5][k & 31] = VL[(size_t)bt * 4096 + k];
    if (tid < 128) { sM[tid] = M2[bt * 128 + tid]; sSi[tid] = 1.f / S2[bt * 128 + tid]; }
    if (tid < 8)   sAB[tid] = (tid < 4) ? sigmoidf_(alpha[tid]) : sigmoidf_(beta[tid - 4]);
    __syncthreads();
    {
        int ti2 = tid >> 5, f4 = (tid & 31) * 4;
        us4 lv = *(const us4*)&Lb[(size_t)(tk0 + ti2) * 128 + f4];
#pragma unroll
        for (int j = 0; j < 4; ++j)
            sP[ti2][f4 + j] = __expf(bu2f(lv[j]) - sM[f4 + j]) * sSi[f4 + j];
    }
    __syncthreads();
    int ti = tid >> 5, quad = tid & 31;
    int h = quad >> 3, d0 = (quad & 7) * 4;
    float a0 = 0, a1 = 0, a2 = 0, a3 = 0;
    int hr0 = h * 32;
#pragma unroll 4
    for (int r = 0; r < 32; ++r) {
        float p = sP[ti][hr0 + r];
        float4 v = *(const float4*)&sVL[hr0 + r][d0];
        a0 = fmaf(p, v.x, a0); a1 = fmaf(p, v.y, a1);
        a2 = fmaf(p, v.z, a2); a3 = fmaf(p, v.w, a3);
    }
    size_t gi = (size_t)(tk0 + ti) * 128 + quad * 4;
    ushort4 xv4 = *(const ushort4*)&XVb[gi];
    float sa = sAB[h], sb = sAB[4 + h];
    float o0 = fmaf(sb, a0, fmaf(sa, bu2f(xv4.x), x[gi + 0]));
    float o1 = fmaf(sb, a1, fmaf(sa, bu2f(xv4.y), x[gi + 1]));
    float o2 = fmaf(sb, a2, fmaf(sa, bu2f(xv4.z), x[gi + 2]));
    float o3 = fmaf(sb, a3, fmaf(sa, bu2f(xv4.w), x[gi + 3]));
    ushort4 pk; pk.x = f2bu(o0); pk.y = f2bu(o1); pk.z = f2bu(o2); pk.w = f2bu(o3);
    *(ushort4*)&X2b[gi] = pk;
}

// ---------------- K6: MFMA FFN + fused rms2 + final residual ----------------
// block = (b,n), 4 waves, 3 blocks/CU. Wave owns ONE f-tile for the WHOLE
// kernel (xnf 32 regs, oacc = 128t x 32f strip = 64 regs). K-loop over o in
// chunks of 32: H1/H2 (bias-initialized from LDS), silu*mul in-register,
// shfl_xor(32) half-exchange assembles phase-C B-fragments. NO LDS writes,
// NO barriers in the K-loop -> waves drift and overlap freely.
constexpr int XST = 132;                 // xstage row stride (ushorts), 264B
__global__ __launch_bounds__(256, 3) void k_ffn_mfma(
    const unsigned short* __restrict__ X2b, const float* __restrict__ nw,
    const unsigned short* __restrict__ w1b, const float* __restrict__ b1,
    const unsigned short* __restrict__ w2b, const float* __restrict__ b2,
    const unsigned short* __restrict__ w3b, const float* __restrict__ b3,
    float* __restrict__ out)
{
    __shared__ unsigned short xstage[128 * XST] __attribute__((aligned(16)));  // 33792 B
    __shared__ float sscale[128];
    __shared__ float sb1[512], sb2[512];

    const int tid  = threadIdx.x;
    const int lane = tid & 63;
    const int wv   = tid >> 6;
    const int lr   = lane & 31;
    const int lhi  = lane >> 5;
    const int blk  = blockIdx.x;
    const int b    = blk >> 10, n = blk & 1023;

    // ---- stage X2 column-slab into LDS transposed + stage b1/b2 ----
    const unsigned short* xg = X2b + ((size_t)(b * Tc) * Nc + n) * 128;
#pragma unroll
    for (int p = 0; p < 8; ++p) {
        int i = p * 256 + tid;
        int t = i >> 4, fg = i & 15;
        us8 v = *(const us8*)(xg + (size_t)t * NF + fg * 8);
        int tt = t ^ ((fg & 7) << 3);
#pragma unroll
        for (int j = 0; j < 8; ++j) xstage[(fg * 8 + j) * XST + tt] = v[j];
    }
#pragma unroll
    for (int i = tid; i < 512; i += 256) { sb1[i] = b1[i]; sb2[i] = b2[i]; }
    __syncthreads();

    // ---- fused rms2 (linear row reads; swizzle-oblivious full-row sum) ----
    {
        const int frow = tid >> 1, half = tid & 1;
        float ss = 0.f;
#pragma unroll
        for (int kk = 0; kk < 16; ++kk) {
            us4 u = *(const us4*)&xstage[frow * XST + half * 64 + kk * 4];
#pragma unroll
            for (int j = 0; j < 4; ++j) { float v = bu2f(u[j]); ss = fmaf(v, v, ss); }
        }
        ss += __shfl_xor(ss, 1);
        if (half == 0) sscale[frow] = rsqrtf(ss * (1.f / Tc) + EPSc) * nw[frow];
    }
    __syncthreads();

    // ---- build this wave's XN B-fragments (its f-tile of 32) ----
    const int fcol = wv * 32 + lr;
    bf16x8 xnf[8];
    {
        const int swz = ((fcol >> 3) & 7) << 3;
        const float scale = sscale[fcol];
#pragma unroll
        for (int s = 0; s < 8; ++s) {
            int tb = (s * 16 + lhi * 8) ^ swz;
            us4 u0 = *(const us4*)&xstage[fcol * XST + tb];
            us4 u1 = *(const us4*)&xstage[fcol * XST + tb + 4];
            bf16x8 v;
#pragma unroll
            for (int j = 0; j < 4; ++j) {
                v[j]     = (__bf16)(bu2f(u0[j]) * scale);
                v[j + 4] = (__bf16)(bu2f(u1[j]) * scale);
            }
            xnf[s] = v;
        }
    }

    // ---- oacc init: residual + b3 (wave's strip: t = c*32+rowmap, f = fcol) ----
    f32x16 oacc[4];
    {
        const int swz = ((fcol >> 3) & 7) << 3;
#pragma unroll
        for (int c = 0; c < 4; ++c) {
#pragma unroll
            for (int q = 0; q < 4; ++q) {
                const int tb = c * 32 + 8 * q + 4 * lhi;
                us4 u = *(const us4*)&xstage[fcol * XST + (tb ^ swz)];
#pragma unroll
                for (int e = 0; e < 4; ++e)
                    oacc[c][q * 4 + e] = bu2f(u[e]) + b3[tb + e];
            }
        }
    }
    // No further LDS writes -> no more barriers needed; waves run free.

    const bool hi = (lhi != 0);
    for (int oc = 0; oc < 512; oc += 32) {
        // ---- phase B: H1/H2 = W1/W2[oc..oc+31] @ XN(f-tile), bias-init ----
        f32x16 h1, h2;
#pragma unroll
        for (int q = 0; q < 4; ++q) {
            float4 bb1 = *(const float4*)&sb1[oc + 8 * q + 4 * lhi];
            float4 bb2 = *(const float4*)&sb2[oc + 8 * q + 4 * lhi];
            h1[q * 4 + 0] = bb1.x; h1[q * 4 + 1] = bb1.y; h1[q * 4 + 2] = bb1.z; h1[q * 4 + 3] = bb1.w;
            h2[q * 4 + 0] = bb2.x; h2[q * 4 + 1] = bb2.y; h2[q * 4 + 2] = bb2.z; h2[q * 4 + 3] = bb2.w;
        }
        const unsigned short* pw1 = w1b + (size_t)(oc + lr) * 128 + lhi * 8;
        const unsigned short* pw2 = w2b + (size_t)(oc + lr) * 128 + lhi * 8;
#pragma unroll
        for (int s = 0; s < 8; ++s) {
            bf16x8 a1 = *(const bf16x8*)(pw1 + s * 16);
            bf16x8 a2 = *(const bf16x8*)(pw2 + s * 16);
            h1 = __builtin_amdgcn_mfma_f32_32x32x16_bf16(a1, xnf[s], h1, 0, 0, 0);
            h2 = __builtin_amdgcn_mfma_f32_32x32x16_bf16(a2, xnf[s], h2, 0, 0, 0);
        }
        // ---- g = silu(h1)*h2 in-register ----
        float gv[16];
#pragma unroll
        for (int r = 0; r < 16; ++r) {
            float z = h1[r];
            gv[r] = z * sigmoidf_(z) * h2[r];
        }
        // ---- assemble phase-C B-fragments via half-wave exchange ----
        unsigned A0 = pk2(gv[0],  gv[1]),  A1 = pk2(gv[2],  gv[3]);
        unsigned B0 = pk2(gv[4],  gv[5]),  B1 = pk2(gv[6],  gv[7]);
        unsigned C0 = pk2(gv[8],  gv[9]),  C1 = pk2(gv[10], gv[11]);
        unsigned D0 = pk2(gv[12], gv[13]), D1 = pk2(gv[14], gv[15]);
        unsigned R0 = __shfl_xor(hi ? A0 : B0, 32, 64);
        unsigned R1 = __shfl_xor(hi ? A1 : B1, 32, 64);
        unsigned R2 = __shfl_xor(hi ? C0 : D0, 32, 64);
        unsigned R3 = __shfl_xor(hi ? C1 : D1, 32, 64);
        uint4 f0, f1;
        f0.x = hi ? R0 : A0;  f0.y = hi ? R1 : A1;
        f0.z = hi ? B0 : R0;  f0.w = hi ? B1 : R1;
        f1.x = hi ? R2 : C0;  f1.y = hi ? R3 : C1;
        f1.z = hi ? D0 : R2;  f1.w = hi ? D1 : R3;
        bf16x8 g0 = __builtin_bit_cast(bf16x8, f0);
        bf16x8 g1 = __builtin_bit_cast(bf16x8, f1);
        // ---- phase C: OUT strip += W3[:, oc..oc+31] * G ----
#pragma unroll
        for (int c = 0; c < 4; ++c) {
            const unsigned short* pw3 = w3b + (size_t)(c * 32 + lr) * 512 + oc + lhi * 8;
            bf16x8 a3k0 = *(const bf16x8*)(pw3);
            bf16x8 a3k1 = *(const bf16x8*)(pw3 + 16);
            oacc[c] = __builtin_amdgcn_mfma_f32_32x32x16_bf16(a3k0, g0, oacc[c], 0, 0, 0);
            oacc[c] = __builtin_amdgcn_mfma_f32_32x32x16_bf16(a3k1, g1, oacc[c], 0, 0, 0);
        }
    }

    // ---- epilogue: out = oacc (residual+b3 already folded in) ----
#pragma unroll
    for (int c = 0; c < 4; ++c) {
#pragma unroll
        for (int r = 0; r < 16; ++r) {
            const int t = c * 32 + (r & 3) + 8 * (r >> 2) + 4 * lhi;
            out[((size_t)(b * Tc + t) * Nc + n) * 128 + fcol] = oacc[c][r];
        }
    }
}

extern "C" void kernel_launch(void* const* d_in, const int* in_sizes, int n_in,
                              void* d_out, int out_size, void* d_ws, size_t ws_size,
                              hipStream_t stream) {
    const float* x      = (const float*)d_in[0];
    const float* norm_w = (const float*)d_in[1];
    const float* q_w    = (const float*)d_in[2];
    const float* q_b    = (const float*)d_in[3];
    const float* key_p  = (const float*)d_in[4];
    const float* v_w    = (const float*)d_in[5];
    const float* v_b    = (const float*)d_in[6];
    const float* alpha  = (const float*)d_in[7];
    const float* beta   = (const float*)d_in[8];
    const float* w1     = (const float*)d_in[9];
    const float* b1     = (const float*)d_in[10];
    const float* w2     = (const float*)d_in[11];
    const float* b2     = (const float*)d_in[12];
    const float* w3     = (const float*)d_in[13];
    const float* b3     = (const float*)d_in[14];
    float* out = (float*)d_out;

    char* ws = (char*)d_ws;
    float* inv1 = (float*)ws;                                    // 262144 f
    float* inv2 = inv1 + (size_t)Bc * NF;                        // 262144 f (spare)
    float* VLp  = inv2 + (size_t)Bc * NF;                        // 1048576 f
    float* M2p  = VLp + (size_t)Bc * Tc * Hc * Rc * Dc;          // 32768 f
    float* S2p  = M2p + (size_t)Bc * Tc * Hc * Rc;               // 32768 f
    unsigned short* Lb  = (unsigned short*)(S2p + (size_t)Bc * Tc * Hc * Rc);
    unsigned short* XVb = Lb  + (size_t)TOK * 128;
    unsigned short* X2b = XVb + (size_t)TOK * 128;               // total ~198.3 MiB

    // Wcat (256x128 bf16) + bias (256 f) alias the VLp region (VL written later by k_land)
    unsigned short* Wcat = (unsigned short*)VLp;                 // 32768 us = 16384 f
    float* bias256 = VLp + 16384;

    // bf16 weight copies alias Lb (dead after k_out1)
    unsigned short* w1bf = Lb;
    unsigned short* w2bf = Lb + 65536;
    unsigned short* w3bf = Lb + 131072;

    k_rms_f32 <<<Bc * NF / 256, 256, 0, stream>>>(x, inv1);
    k_qk      <<<68,            256, 0, stream>>>(q_w, q_b, key_p, v_b, v_w, Wcat, bias256);
    k_projm   <<<TOK / 128,     256, 0, stream>>>(x, inv1, norm_w, Wcat, bias256, Lb, XVb);
    k_land    <<<Bc * Tc * Hc,  256, 0, stream>>>(Lb, XVb, VLp, M2p, S2p);
    k_out1    <<<TOK / 8,       256, 0, stream>>>(x, Lb, XVb, VLp, M2p, S2p, alpha, beta, X2b);
    k_cvt3    <<<768,           256, 0, stream>>>(w1, w2, w3, w1bf);
    k_ffn_mfma<<<Bc * Nc,       256, 0, stream>>>(X2b, norm_w, w1bf, b1, w2bf, b2, w3bf, b3, out);
}

// Round 11
// 629.203 us; speedup vs baseline: 1.1623x; 1.1623x over previous
//
#include <hip/hip_runtime.h>

#define DEV static __device__ __forceinline__

constexpr int Bc = 2, Tc = 128, Nc = 1024, Fc = 128, Hc = 4, Rc = 32, Dc = 32;
constexpr int NF  = Nc * Fc;        // 131072 = 2^17
constexpr int TOK = Bc * Tc * Nc;   // 262144
constexpr float EPSc = 1e-6f;
constexpr float RSD  = 0.17677669529663687f;  // 1/sqrt(32)

typedef __bf16 bf16x8 __attribute__((ext_vector_type(8)));
typedef float  f32x16 __attribute__((ext_vector_type(16)));
typedef unsigned short us8 __attribute__((ext_vector_type(8)));
typedef unsigned short us4 __attribute__((ext_vector_type(4)));

DEV unsigned short f2bu(float f) {              // fp32 -> bf16 (RNE)
    unsigned u = __builtin_bit_cast(unsigned, f);
    u += 0x7fffu + ((u >> 16) & 1u);
    return (unsigned short)(u >> 16);
}
DEV float bu2f(unsigned short s) {
    return __builtin_bit_cast(float, ((unsigned)s) << 16);
}
DEV float sigmoidf_(float z) { return 1.f / (1.f + __expf(-z)); }
DEV f32x16 zero16() { f32x16 z;
#pragma unroll
    for (int i = 0; i < 16; i++) z[i] = 0.f;
    return z; }

// ---------------- K1: rmsnorm-over-t scale factors (for x fp32) -----------------
__global__ void k_rms_f32(const float* __restrict__ x, float* __restrict__ inv) {
    int j = blockIdx.x * 256 + threadIdx.x;     // j = b*NF + p
    int b = j >> 17;
    int p = j & (NF - 1);
    const float* px = x + (size_t)b * Tc * NF + p;
    float s = 0.f;
#pragma unroll 8
    for (int t = 0; t < Tc; ++t) { float v = px[(size_t)t * NF]; s = fmaf(v, v, s); }
    inv[j] = rsqrtf(s * (1.f / Tc) + EPSc);
}

// ---------------- weight fp32 -> bf16 conversions (w1,w2,w3 fused) ----------------
__global__ void k_cvt3(const float* __restrict__ w1, const float* __restrict__ w2,
                       const float* __restrict__ w3, unsigned short* __restrict__ o) {
    int i = blockIdx.x * 256 + threadIdx.x;     // 196608 total
    float v;
    if (i < 65536)       v = w1[i];
    else if (i < 131072) v = w2[i - 65536];
    else                 v = w3[i - 131072];
    o[i] = f2bu(v);
}

// ---------------- K_qk: fold q_w,key_p into QK + v_w cvt + biases ----------------
__global__ void k_qk(const float* __restrict__ q_w, const float* __restrict__ q_b,
                     const float* __restrict__ key_p, const float* __restrict__ v_b,
                     const float* __restrict__ v_w,
                     unsigned short* __restrict__ Wcat, float* __restrict__ bias)
{
    int blk = blockIdx.x, tid = threadIdx.x;
    if (blk >= 4) {
        int i = (blk - 4) * 256 + tid;           // 0..16383
        Wcat[16384 + i] = f2bu(v_w[i]);
        return;
    }
    __shared__ float sqw[32][128];   // [d][c] for this h
    __shared__ float skp[32][32];    // [r][d], pre-scaled by RSD
    int h = blk;
    for (int i = tid; i < 4096; i += 256) {
        int d = i >> 7, c = i & 127;
        sqw[d][c] = q_w[(size_t)(h * 32 + d) * 128 + c];
    }
    for (int i = tid; i < 1024; i += 256) {
        int r = i >> 5, d = i & 31;
        skp[r][d] = key_p[(size_t)(r * 4 + h) * 32 + d] * RSD;
    }
    __syncthreads();
    int r = tid >> 3;
    int c0 = (tid & 7) * 16;
    for (int cc = 0; cc < 16; ++cc) {
        int c = c0 + cc;
        float s = 0.f;
#pragma unroll
        for (int d = 0; d < 32; ++d) s = fmaf(sqw[d][c], skp[r][d], s);
        Wcat[(size_t)(h * 32 + r) * 128 + c] = f2bu(s);
    }
    if (tid < 32) {
        float s = 0.f;
#pragma unroll
        for (int d = 0; d < 32; ++d) s = fmaf(q_b[h * 32 + d], skp[tid][d], s);
        bias[h * 32 + tid] = s;
    }
    if (h == 0 && tid >= 64 && tid < 192) bias[128 + tid - 64] = v_b[tid - 64];
}

// ---------------- K2: MFMA projection: [L ; XV] = XN @ Wcat^T + bias ----------------
__global__ __launch_bounds__(256, 4) void k_projm(
    const float* __restrict__ x, const float* __restrict__ inv1, const float* __restrict__ nw,
    const unsigned short* __restrict__ Wcat, const float* __restrict__ bias,
    unsigned short* __restrict__ Lb, unsigned short* __restrict__ XVb)
{
    const int tid = threadIdx.x, lane = tid & 63, wv = tid >> 6;
    const int lr = lane & 31, lhi = lane >> 5;
    const int tokb = blockIdx.x * 128 + wv * 32;
    const int tok = tokb + lr;
    const int b = tok >> 17, n = tok & 1023;
    const float* px = x + (size_t)tok * 128;
    const float* pi = inv1 + (size_t)b * NF + n * 128;

    bf16x8 af[8];
#pragma unroll
    for (int s = 0; s < 8; ++s) {
        const int c0 = s * 16 + lhi * 8;
        float4 xa = *(const float4*)(px + c0);
        float4 xb = *(const float4*)(px + c0 + 4);
        float4 ia = *(const float4*)(pi + c0);
        float4 ib = *(const float4*)(pi + c0 + 4);
        float4 na = *(const float4*)(nw + c0);
        float4 nb = *(const float4*)(nw + c0 + 4);
        bf16x8 v;
        v[0] = (__bf16)(xa.x * ia.x * na.x);
        v[1] = (__bf16)(xa.y * ia.y * na.y);
        v[2] = (__bf16)(xa.z * ia.z * na.z);
        v[3] = (__bf16)(xa.w * ia.w * na.w);
        v[4] = (__bf16)(xb.x * ib.x * nb.x);
        v[5] = (__bf16)(xb.y * ib.y * nb.y);
        v[6] = (__bf16)(xb.z * ib.z * nb.z);
        v[7] = (__bf16)(xb.w * ib.w * nb.w);
        af[s] = v;
    }

#pragma unroll
    for (int ot = 0; ot < 8; ++ot) {
        const unsigned short* pw = Wcat + (size_t)(ot * 32 + lr) * 128 + lhi * 8;
        f32x16 acc = zero16();
#pragma unroll
        for (int s = 0; s < 8; ++s) {
            bf16x8 bw = *(const bf16x8*)(pw + s * 16);
            acc = __builtin_amdgcn_mfma_f32_32x32x16_bf16(af[s], bw, acc, 0, 0, 0);
        }
        const int o = ot * 32 + lr;
        const float bv = bias[o];
        unsigned short* dst = (ot < 4) ? Lb : XVb;
        const int oo = (ot < 4) ? o : o - 128;
#pragma unroll
        for (int r = 0; r < 16; ++r) {
            const int trow = tokb + (r & 3) + 8 * (r >> 2) + 4 * lhi;
            dst[(size_t)trow * 128 + oo] = f2bu(acc[r] + bv);
        }
    }
}

// ---------------- K3: landmark aggregation + n-softmax stats (parallel, vec loads) ----------------
__global__ __launch_bounds__(256, 4) void k_land(
    const unsigned short* __restrict__ Lb, const unsigned short* __restrict__ XVb,
    float* __restrict__ VL, float* __restrict__ M2, float* __restrict__ S2)
{
    __shared__ float sL [64][34];
    __shared__ float sXV[64][36];
    __shared__ float redm[32][8];
    __shared__ float reds[32][8];
    int tid = threadIdx.x;
    int blk = blockIdx.x;               // bt*4 + h
    int h = blk & 3; int bt = blk >> 2;
    size_t base = (size_t)bt * Nc * 128 + h * 32;
    const int li = tid >> 2, c8 = (tid & 3) * 8;      // load mapping (us8)
    const int r_st = tid & 31, stripe = tid >> 5;     // stats mapping
    const int ti = tid >> 2, sub = tid & 3;           // p1 mapping
    const int r_acc = tid >> 3, d0 = (tid & 7) * 4;   // VL mapping
    float m_st = -1e30f, s_st = 0.f;
    float a0 = 0, a1 = 0, a2 = 0, a3 = 0;
    for (int n0 = 0; n0 < Nc; n0 += 64) {
        {
            size_t g = base + (size_t)(n0 + li) * 128 + c8;
            us8 vL = *(const us8*)(Lb + g);
            us8 vX = *(const us8*)(XVb + g);
#pragma unroll
            for (int j = 0; j < 8; ++j) {
                sL [li][c8 + j] = bu2f(vL[j]);
                sXV[li][c8 + j] = bu2f(vX[j]);
            }
        }
        __syncthreads();
#pragma unroll
        for (int i8 = 0; i8 < 8; ++i8) {
            float v = sL[stripe * 8 + i8][r_st];
            float mn = fmaxf(m_st, v);
            s_st = s_st * __expf(m_st - mn) + __expf(v - mn);
            m_st = mn;
        }
        float e[8];
        float mx = -1e30f;
#pragma unroll
        for (int j = 0; j < 8; ++j) mx = fmaxf(mx, sL[ti][sub * 8 + j]);
        mx = fmaxf(mx, __shfl_xor(mx, 1));
        mx = fmaxf(mx, __shfl_xor(mx, 2));
        float sm = 0.f;
#pragma unroll
        for (int j = 0; j < 8; ++j) { e[j] = __expf(sL[ti][sub * 8 + j] - mx); sm += e[j]; }
        sm += __shfl_xor(sm, 1);
        sm += __shfl_xor(sm, 2);
        float iv = 1.f / sm;
        __syncthreads();                 // all reads of sL done
#pragma unroll
        for (int j = 0; j < 8; ++j) sL[ti][sub * 8 + j] = e[j] * iv;
        __syncthreads();
#pragma unroll 2
        for (int i = 0; i < 64; ++i) {
            float p = sL[i][r_acc];
            float4 v = *(const float4*)&sXV[i][d0];
            a0 = fmaf(p, v.x, a0); a1 = fmaf(p, v.y, a1);
            a2 = fmaf(p, v.z, a2); a3 = fmaf(p, v.w, a3);
        }
        __syncthreads();
    }
    redm[r_st][stripe] = m_st;
    reds[r_st][stripe] = s_st;
    __syncthreads();
    if (tid < 32) {
        float m = -1e30f;
#pragma unroll
        for (int k = 0; k < 8; ++k) m = fmaxf(m, redm[tid][k]);
        float s = 0.f;
#pragma unroll
        for (int k = 0; k < 8; ++k) s += reds[tid][k] * __expf(redm[tid][k] - m);
        M2[blk * 32 + tid] = m;
        S2[blk * 32 + tid] = s;
    }
    *(float4*)&VL[((size_t)blk * 32 + r_acc) * 32 + d0] = make_float4(a0, a1, a2, a3);
}

// ---------------- K4: scatter landmarks + gates + first residual ----------------
__global__ void k_out1(const float* __restrict__ x,
                       const unsigned short* __restrict__ Lb, const unsigned short* __restrict__ XVb,
                       const float* __restrict__ VL, const float* __restrict__ M2, const float* __restrict__ S2,
                       const float* __restrict__ alpha, const float* __restrict__ beta,
                       unsigned short* __restrict__ X2b)
{
    __shared__ float sVL[128][32];
    __shared__ float sP[8][128];
    __shared__ float sM[128], sSi[128], sAB[8];
    int tid = threadIdx.x;
    int tk0 = blockIdx.x * 8;
    int bt = tk0 >> 10;
    for (int k = tid; k < 4096; k += 256) sVL[k >> 5][k & 31] = VL[(size_t)bt * 4096 + k];
    if (tid < 128) { sM[tid] = M2[bt * 128 + tid]; sSi[tid] = 1.f / S2[bt * 128 + tid]; }
    if (tid < 8)   sAB[tid] = (tid < 4) ? sigmoidf_(alpha[tid]) : sigmoidf_(beta[tid - 4]);
    __syncthreads();
    {
        int ti2 = tid >> 5, f4 = (tid & 31) * 4;
        us4 lv = *(const us4*)&Lb[(size_t)(tk0 + ti2) * 128 + f4];
#pragma unroll
        for (int j = 0; j < 4; ++j)
            sP[ti2][f4 + j] = __expf(bu2f(lv[j]) - sM[f4 + j]) * sSi[f4 + j];
    }
    __syncthreads();
    int ti = tid >> 5, quad = tid & 31;
    int h = quad >> 3, d0 = (quad & 7) * 4;
    float a0 = 0, a1 = 0, a2 = 0, a3 = 0;
    int hr0 = h * 32;
#pragma unroll 4
    for (int r = 0; r < 32; ++r) {
        float p = sP[ti][hr0 + r];
        float4 v = *(const float4*)&sVL[hr0 + r][d0];
        a0 = fmaf(p, v.x, a0); a1 = fmaf(p, v.y, a1);
        a2 = fmaf(p, v.z, a2); a3 = fmaf(p, v.w, a3);
    }
    size_t gi = (size_t)(tk0 + ti) * 128 + quad * 4;
    ushort4 xv4 = *(const ushort4*)&XVb[gi];
    float sa = sAB[h], sb = sAB[4 + h];
    float o0 = fmaf(sb, a0, fmaf(sa, bu2f(xv4.x), x[gi + 0]));
    float o1 = fmaf(sb, a1, fmaf(sa, bu2f(xv4.y), x[gi + 1]));
    float o2 = fmaf(sb, a2, fmaf(sa, bu2f(xv4.z), x[gi + 2]));
    float o3 = fmaf(sb, a3, fmaf(sa, bu2f(xv4.w), x[gi + 3]));
    ushort4 pk; pk.x = f2bu(o0); pk.y = f2bu(o1); pk.z = f2bu(o2); pk.w = f2bu(o3);
    *(ushort4*)&X2b[gi] = pk;
}

// ---------------- K6: MFMA FFN + fused rms2 + final residual (pipelined) ----------------
// block = (b,n), 4 waves, 2 blocks/CU. 16 o-sub-chunks of 32; TWO h-sets so
// phase-B MFMAs of sub i+1 co-schedule with silu(i) (independent). Phase C =
// third independent MFMA stream. gT dbuf + 2-bit XOR swizzle (conflict-free,
// 16B-aligned). Phase-B wave = f-tile (xnf 32 regs); phase-C wave = t-tile.
constexpr int XST = 132;                 // xstage row stride (ushorts)
constexpr int GST = 72;                  // gT row stride (ushorts)
__global__ __launch_bounds__(256, 2) void k_ffn_mfma(
    const unsigned short* __restrict__ X2b, const float* __restrict__ nw,
    const unsigned short* __restrict__ w1b, const float* __restrict__ b1,
    const unsigned short* __restrict__ w2b, const float* __restrict__ b2,
    const unsigned short* __restrict__ w3b, const float* __restrict__ b3,
    float* __restrict__ out)
{
    __shared__ unsigned short smem[2 * 128 * GST] __attribute__((aligned(16))); // 36864 B
    unsigned short* xstage = smem;           // [128][XST] (prologue only)
    unsigned short* gT     = smem;           // [2][128][GST] (K-loop)
    __shared__ float sscale[128];
    __shared__ float sb1[512], sb2[512];

    const int tid  = threadIdx.x;
    const int lane = tid & 63;
    const int wv   = tid >> 6;
    const int lr   = lane & 31;
    const int lhi  = lane >> 5;
    const int blk  = blockIdx.x;
    const int b    = blk >> 10, n = blk & 1023;
    const int t0   = wv * 32;           // phase-C t-tile
    const int fcol = wv * 32 + lr;      // phase-B f-column

    // ---- stage X2 column-slab into LDS transposed: xstage[f][t ^ swz(f)] ----
    const unsigned short* xg = X2b + ((size_t)(b * Tc) * Nc + n) * 128;
#pragma unroll
    for (int p = 0; p < 8; ++p) {
        int i = p * 256 + tid;
        int t = i >> 4, fg = i & 15;
        us8 v = *(const us8*)(xg + (size_t)t * NF + fg * 8);
        int tt = t ^ ((fg & 7) << 3);
#pragma unroll
        for (int j = 0; j < 8; ++j) xstage[(fg * 8 + j) * XST + tt] = v[j];
    }
#pragma unroll
    for (int i = tid; i < 512; i += 256) { sb1[i] = b1[i]; sb2[i] = b2[i]; }
    __syncthreads();

    // ---- fused rms2 ----
    {
        const int frow = tid >> 1, half = tid & 1;
        float ss = 0.f;
#pragma unroll
        for (int kk = 0; kk < 16; ++kk) {
            us4 u = *(const us4*)&xstage[frow * XST + half * 64 + kk * 4];
#pragma unroll
            for (int j = 0; j < 4; ++j) { float v = bu2f(u[j]); ss = fmaf(v, v, ss); }
        }
        ss += __shfl_xor(ss, 1);
        if (half == 0) sscale[frow] = rsqrtf(ss * (1.f / Tc) + EPSc) * nw[frow];
    }
    __syncthreads();

    // ---- build this wave's XN B-fragments (its f-tile) ----
    bf16x8 xnf[8];
    {
        const int swz = ((fcol >> 3) & 7) << 3;
        const float scale = sscale[fcol];
#pragma unroll
        for (int s = 0; s < 8; ++s) {
            int tb = (s * 16 + lhi * 8) ^ swz;
            us4 u0 = *(const us4*)&xstage[fcol * XST + tb];
            us4 u1 = *(const us4*)&xstage[fcol * XST + tb + 4];
            bf16x8 v;
#pragma unroll
            for (int j = 0; j < 4; ++j) {
                v[j]     = (__bf16)(bu2f(u0[j]) * scale);
                v[j + 4] = (__bf16)(bu2f(u1[j]) * scale);
            }
            xnf[s] = v;
        }
    }

    // ---- oacc init: residual + b3 (t = t0 + rowmap, f = c*32+lr) ----
    f32x16 oacc[4];
#pragma unroll
    for (int c = 0; c < 4; ++c) {
        const int f = c * 32 + lr;
        const int swz = ((f >> 3) & 7) << 3;
#pragma unroll
        for (int q = 0; q < 4; ++q) {
            const int tb = t0 + 8 * q + 4 * lhi;
            us4 u = *(const us4*)&xstage[f * XST + (tb ^ swz)];
#pragma unroll
            for (int e = 0; e < 4; ++e)
                oacc[c][q * 4 + e] = bu2f(u[e]) + b3[tb + e];
        }
    }
    __syncthreads();    // xstage dead; gT may now be written

    const unsigned short* w3r = w3b + (size_t)(t0 + lr) * 512 + lhi * 8;
    const int gswz = ((lr >> 3) & 3) << 3;               // write-side o-swizzle

    auto PHASE_B = [&](f32x16& h1, f32x16& h2, int oc) {
#pragma unroll
        for (int q = 0; q < 4; ++q) {
            float4 bb1 = *(const float4*)&sb1[oc + 8 * q + 4 * lhi];
            float4 bb2 = *(const float4*)&sb2[oc + 8 * q + 4 * lhi];
            h1[q * 4 + 0] = bb1.x; h1[q * 4 + 1] = bb1.y; h1[q * 4 + 2] = bb1.z; h1[q * 4 + 3] = bb1.w;
            h2[q * 4 + 0] = bb2.x; h2[q * 4 + 1] = bb2.y; h2[q * 4 + 2] = bb2.z; h2[q * 4 + 3] = bb2.w;
        }
        const unsigned short* pw1 = w1b + (size_t)(oc + lr) * 128 + lhi * 8;
        const unsigned short* pw2 = w2b + (size_t)(oc + lr) * 128 + lhi * 8;
#pragma unroll
        for (int s = 0; s < 8; ++s) {
            bf16x8 a1 = *(const bf16x8*)(pw1 + s * 16);
            bf16x8 a2 = *(const bf16x8*)(pw2 + s * 16);
            h1 = __builtin_amdgcn_mfma_f32_32x32x16_bf16(a1, xnf[s], h1, 0, 0, 0);
            h2 = __builtin_amdgcn_mfma_f32_32x32x16_bf16(a2, xnf[s], h2, 0, 0, 0);
        }
    };
    auto SILU_STORE = [&](const f32x16& h1, const f32x16& h2, unsigned short* gTd) {
#pragma unroll
        for (int q = 0; q < 4; ++q) {
            ushort4 pk;
#pragma unroll
            for (int e = 0; e < 4; ++e) {
                const int r = q * 4 + e;
                float z = h1[r];
                float g = z * sigmoidf_(z) * h2[r];
                unsigned short gb = f2bu(g);
                if (e == 0) pk.x = gb; else if (e == 1) pk.y = gb;
                else if (e == 2) pk.z = gb; else pk.w = gb;
            }
            const int o_l = (8 * q + 4 * lhi) ^ gswz;
            *(ushort4*)&gTd[fcol * GST + o_l] = pk;
        }
    };
    auto PHASE_C = [&](const unsigned short* gTd, const bf16x8* a3) {
#pragma unroll
        for (int s = 0; s < 2; ++s) {
#pragma unroll
            for (int c = 0; c < 4; ++c) {
                const int off = (s * 16 + lhi * 8) ^ gswz;     // f-row = c*32+lr shares lr-swizzle
                bf16x8 bg = *(const bf16x8*)&gTd[(c * 32 + lr) * GST + off];
                oacc[c] = __builtin_amdgcn_mfma_f32_32x32x16_bf16(a3[s], bg, oacc[c], 0, 0, 0);
            }
        }
    };

    f32x16 h1A, h2A, h1B, h2B;
    PHASE_B(h1A, h2A, 0);
    for (int i = 0; i < 16; i += 2) {
        // ---- even sub-chunk i (regs A, buffer 0) ----
        unsigned short* g0 = gT;
        bf16x8 a3[2];
        a3[0] = *(const bf16x8*)(w3r + i * 32);
        a3[1] = *(const bf16x8*)(w3r + i * 32 + 16);
        PHASE_B(h1B, h2B, (i + 1) * 32);           // next sub-chunk, independent of silu(A)
        SILU_STORE(h1A, h2A, g0);
        __syncthreads();
        PHASE_C(g0, a3);
        // ---- odd sub-chunk i+1 (regs B, buffer 1) ----
        unsigned short* g1 = gT + 128 * GST;
        a3[0] = *(const bf16x8*)(w3r + (i + 1) * 32);
        a3[1] = *(const bf16x8*)(w3r + (i + 1) * 32 + 16);
        if (i + 2 < 16) PHASE_B(h1A, h2A, (i + 2) * 32);
        SILU_STORE(h1B, h2B, g1);
        __syncthreads();
        PHASE_C(g1, a3);
    }

    // ---- epilogue: out = oacc (residual+b3 already folded in) ----
#pragma unroll
    for (int r = 0; r < 16; ++r) {
        const int t = t0 + (r & 3) + 8 * (r >> 2) + 4 * lhi;
        const size_t rowbase = ((size_t)(b * Tc + t) * Nc + n) * 128;
#pragma unroll
        for (int c = 0; c < 4; ++c) {
            out[rowbase + c * 32 + lr] = oacc[c][r];
        }
    }
}

extern "C" void kernel_launch(void* const* d_in, const int* in_sizes, int n_in,
                              void* d_out, int out_size, void* d_ws, size_t ws_size,
                              hipStream_t stream) {
    const float* x      = (const float*)d_in[0];
    const float* norm_w = (const float*)d_in[1];
    const float* q_w    = (const float*)d_in[2];
    const float* q_b    = (const float*)d_in[3];
    const float* key_p  = (const float*)d_in[4];
    const float* v_w    = (const float*)d_in[5];
    const float* v_b    = (const float*)d_in[6];
    const float* alpha  = (const float*)d_in[7];
    const float* beta   = (const float*)d_in[8];
    const float* w1     = (const float*)d_in[9];
    const float* b1     = (const float*)d_in[10];
    const float* w2     = (const float*)d_in[11];
    const float* b2     = (const float*)d_in[12];
    const float* w3     = (const float*)d_in[13];
    const float* b3     = (const float*)d_in[14];
    float* out = (float*)d_out;

    char* ws = (char*)d_ws;
    float* inv1 = (float*)ws;                                    // 262144 f
    float* inv2 = inv1 + (size_t)Bc * NF;                        // 262144 f (spare)
    float* VLp  = inv2 + (size_t)Bc * NF;                        // 1048576 f
    float* M2p  = VLp + (size_t)Bc * Tc * Hc * Rc * Dc;          // 32768 f
    float* S2p  = M2p + (size_t)Bc * Tc * Hc * Rc;               // 32768 f
    unsigned short* Lb  = (unsigned short*)(S2p + (size_t)Bc * Tc * Hc * Rc);
    unsigned short* XVb = Lb  + (size_t)TOK * 128;
    unsigned short* X2b = XVb + (size_t)TOK * 128;               // total ~198.3 MiB

    unsigned short* Wcat = (unsigned short*)VLp;                 // 32768 us
    float* bias256 = VLp + 16384;

    unsigned short* w1bf = Lb;
    unsigned short* w2bf = Lb + 65536;
    unsigned short* w3bf = Lb + 131072;

    k_rms_f32 <<<Bc * NF / 256, 256, 0, stream>>>(x, inv1);
    k_qk      <<<68,            256, 0, stream>>>(q_w, q_b, key_p, v_b, v_w, Wcat, bias256);
    k_projm   <<<TOK / 128,     256, 0, stream>>>(x, inv1, norm_w, Wcat, bias256, Lb, XVb);
    k_land    <<<Bc * Tc * Hc,  256, 0, stream>>>(Lb, XVb, VLp, M2p, S2p);
    k_out1    <<<TOK / 8,       256, 0, stream>>>(x, Lb, XVb, VLp, M2p, S2p, alpha, beta, X2b);
    k_cvt3    <<<768,           256, 0, stream>>>(w1, w2, w3, w1bf);
    k_ffn_mfma<<<Bc * Nc,       256, 0, stream>>>(X2b, norm_w, w1bf, b1, w2bf, b2, w3bf, b3, out);
}

// Round 13
// 535.133 us; speedup vs baseline: 1.3666x; 1.1758x over previous
//
#include <hip/hip_runtime.h>

#define DEV static __device__ __forceinline__

constexpr int Bc = 2, Tc = 128, Nc = 1024, Fc = 128, Hc = 4, Rc = 32, Dc = 32;
constexpr int NF  = Nc * Fc;        // 131072 = 2^17
constexpr int TOK = Bc * Tc * Nc;   // 262144
constexpr float EPSc = 1e-6f;
constexpr float RSD  = 0.17677669529663687f;  // 1/sqrt(32)

typedef __bf16 bf16x8 __attribute__((ext_vector_type(8)));
typedef float  f32x16 __attribute__((ext_vector_type(16)));
typedef unsigned short us8 __attribute__((ext_vector_type(8)));
typedef unsigned short us4 __attribute__((ext_vector_type(4)));

DEV unsigned short f2bu(float f) {              // fp32 -> bf16 (RNE)
    unsigned u = __builtin_bit_cast(unsigned, f);
    u += 0x7fffu + ((u >> 16) & 1u);
    return (unsigned short)(u >> 16);
}
DEV float bu2f(unsigned short s) {
    return __builtin_bit_cast(float, ((unsigned)s) << 16);
}
DEV float sigmoidf_(float z) { return 1.f / (1.f + __expf(-z)); }
DEV f32x16 zero16() { f32x16 z;
#pragma unroll
    for (int i = 0; i < 16; i++) z[i] = 0.f;
    return z; }

// ---------------- K1: rmsnorm-over-t scale factors (for x fp32) -----------------
__global__ void k_rms_f32(const float* __restrict__ x, float* __restrict__ inv) {
    int j = blockIdx.x * 256 + threadIdx.x;     // j = b*NF + p
    int b = j >> 17;
    int p = j & (NF - 1);
    const float* px = x + (size_t)b * Tc * NF + p;
    float s = 0.f;
#pragma unroll 8
    for (int t = 0; t < Tc; ++t) { float v = px[(size_t)t * NF]; s = fmaf(v, v, s); }
    inv[j] = rsqrtf(s * (1.f / Tc) + EPSc);
}

// ---------------- weight fp32 -> bf16 conversions (w1,w2,w3 fused) ----------------
__global__ void k_cvt3(const float* __restrict__ w1, const float* __restrict__ w2,
                       const float* __restrict__ w3, unsigned short* __restrict__ o) {
    int i = blockIdx.x * 256 + threadIdx.x;     // 196608 total
    float v;
    if (i < 65536)       v = w1[i];
    else if (i < 131072) v = w2[i - 65536];
    else                 v = w3[i - 131072];
    o[i] = f2bu(v);
}

// ---------------- K_qk: fold q_w,key_p into QK + v_w cvt + biases ----------------
__global__ void k_qk(const float* __restrict__ q_w, const float* __restrict__ q_b,
                     const float* __restrict__ key_p, const float* __restrict__ v_b,
                     const float* __restrict__ v_w,
                     unsigned short* __restrict__ Wcat, float* __restrict__ bias)
{
    int blk = blockIdx.x, tid = threadIdx.x;
    if (blk >= 4) {
        int i = (blk - 4) * 256 + tid;           // 0..16383
        Wcat[16384 + i] = f2bu(v_w[i]);
        return;
    }
    __shared__ float sqw[32][128];   // [d][c] for this h
    __shared__ float skp[32][32];    // [r][d], pre-scaled by RSD
    int h = blk;
    for (int i = tid; i < 4096; i += 256) {
        int d = i >> 7, c = i & 127;
        sqw[d][c] = q_w[(size_t)(h * 32 + d) * 128 + c];
    }
    for (int i = tid; i < 1024; i += 256) {
        int r = i >> 5, d = i & 31;
        skp[r][d] = key_p[(size_t)(r * 4 + h) * 32 + d] * RSD;
    }
    __syncthreads();
    int r = tid >> 3;
    int c0 = (tid & 7) * 16;
    for (int cc = 0; cc < 16; ++cc) {
        int c = c0 + cc;
        float s = 0.f;
#pragma unroll
        for (int d = 0; d < 32; ++d) s = fmaf(sqw[d][c], skp[r][d], s);
        Wcat[(size_t)(h * 32 + r) * 128 + c] = f2bu(s);
    }
    if (tid < 32) {
        float s = 0.f;
#pragma unroll
        for (int d = 0; d < 32; ++d) s = fmaf(q_b[h * 32 + d], skp[tid][d], s);
        bias[h * 32 + tid] = s;
    }
    if (h == 0 && tid >= 64 && tid < 192) bias[128 + tid - 64] = v_b[tid - 64];
}

// ---------------- K2: MFMA projection: [L ; XV] = XN @ Wcat^T + bias ----------------
__global__ __launch_bounds__(256, 4) void k_projm(
    const float* __restrict__ x, const float* __restrict__ inv1, const float* __restrict__ nw,
    const unsigned short* __restrict__ Wcat, const float* __restrict__ bias,
    unsigned short* __restrict__ Lb, unsigned short* __restrict__ XVb)
{
    const int tid = threadIdx.x, lane = tid & 63, wv = tid >> 6;
    const int lr = lane & 31, lhi = lane >> 5;
    const int tokb = blockIdx.x * 128 + wv * 32;
    const int tok = tokb + lr;
    const int b = tok >> 17, n = tok & 1023;
    const float* px = x + (size_t)tok * 128;
    const float* pi = inv1 + (size_t)b * NF + n * 128;

    bf16x8 af[8];
#pragma unroll
    for (int s = 0; s < 8; ++s) {
        const int c0 = s * 16 + lhi * 8;
        float4 xa = *(const float4*)(px + c0);
        float4 xb = *(const float4*)(px + c0 + 4);
        float4 ia = *(const float4*)(pi + c0);
        float4 ib = *(const float4*)(pi + c0 + 4);
        float4 na = *(const float4*)(nw + c0);
        float4 nb = *(const float4*)(nw + c0 + 4);
        bf16x8 v;
        v[0] = (__bf16)(xa.x * ia.x * na.x);
        v[1] = (__bf16)(xa.y * ia.y * na.y);
        v[2] = (__bf16)(xa.z * ia.z * na.z);
        v[3] = (__bf16)(xa.w * ia.w * na.w);
        v[4] = (__bf16)(xb.x * ib.x * nb.x);
        v[5] = (__bf16)(xb.y * ib.y * nb.y);
        v[6] = (__bf16)(xb.z * ib.z * nb.z);
        v[7] = (__bf16)(xb.w * ib.w * nb.w);
        af[s] = v;
    }

#pragma unroll
    for (int ot = 0; ot < 8; ++ot) {
        const unsigned short* pw = Wcat + (size_t)(ot * 32 + lr) * 128 + lhi * 8;
        f32x16 acc = zero16();
#pragma unroll
        for (int s = 0; s < 8; ++s) {
            bf16x8 bw = *(const bf16x8*)(pw + s * 16);
            acc = __builtin_amdgcn_mfma_f32_32x32x16_bf16(af[s], bw, acc, 0, 0, 0);
        }
        const int o = ot * 32 + lr;
        const float bv = bias[o];
        unsigned short* dst = (ot < 4) ? Lb : XVb;
        const int oo = (ot < 4) ? o : o - 128;
#pragma unroll
        for (int r = 0; r < 16; ++r) {
            const int trow = tokb + (r & 3) + 8 * (r >> 2) + 4 * lhi;
            dst[(size_t)trow * 128 + oo] = f2bu(acc[r] + bv);
        }
    }
}

// ---------------- K3: landmark aggregation + n-softmax stats (parallel, vec loads) ----------------
__global__ __launch_bounds__(256, 4) void k_land(
    const unsigned short* __restrict__ Lb, const unsigned short* __restrict__ XVb,
    float* __restrict__ VL, float* __restrict__ M2, float* __restrict__ S2)
{
    __shared__ float sL [64][34];
    __shared__ float sXV[64][36];
    __shared__ float redm[32][8];
    __shared__ float reds[32][8];
    int tid = threadIdx.x;
    int blk = blockIdx.x;               // bt*4 + h
    int h = blk & 3; int bt = blk >> 2;
    size_t base = (size_t)bt * Nc * 128 + h * 32;
    const int li = tid >> 2, c8 = (tid & 3) * 8;      // load mapping (us8)
    const int r_st = tid & 31, stripe = tid >> 5;     // stats mapping
    const int ti = tid >> 2, sub = tid & 3;           // p1 mapping
    const int r_acc = tid >> 3, d0 = (tid & 7) * 4;   // VL mapping
    float m_st = -1e30f, s_st = 0.f;
    float a0 = 0, a1 = 0, a2 = 0, a3 = 0;
    for (int n0 = 0; n0 < Nc; n0 += 64) {
        {
            size_t g = base + (size_t)(n0 + li) * 128 + c8;
            us8 vL = *(const us8*)(Lb + g);
            us8 vX = *(const us8*)(XVb + g);
#pragma unroll
            for (int j = 0; j < 8; ++j) {
                sL [li][c8 + j] = bu2f(vL[j]);
                sXV[li][c8 + j] = bu2f(vX[j]);
            }
        }
        __syncthreads();
#pragma unroll
        for (int i8 = 0; i8 < 8; ++i8) {
            float v = sL[stripe * 8 + i8][r_st];
            float mn = fmaxf(m_st, v);
            s_st = s_st * __expf(m_st - mn) + __expf(v - mn);
            m_st = mn;
        }
        float e[8];
        float mx = -1e30f;
#pragma unroll
        for (int j = 0; j < 8; ++j) mx = fmaxf(mx, sL[ti][sub * 8 + j]);
        mx = fmaxf(mx, __shfl_xor(mx, 1));
        mx = fmaxf(mx, __shfl_xor(mx, 2));
        float sm = 0.f;
#pragma unroll
        for (int j = 0; j < 8; ++j) { e[j] = __expf(sL[ti][sub * 8 + j] - mx); sm += e[j]; }
        sm += __shfl_xor(sm, 1);
        sm += __shfl_xor(sm, 2);
        float iv = 1.f / sm;
        __syncthreads();                 // all reads of sL done
#pragma unroll
        for (int j = 0; j < 8; ++j) sL[ti][sub * 8 + j] = e[j] * iv;
        __syncthreads();
#pragma unroll 2
        for (int i = 0; i < 64; ++i) {
            float p = sL[i][r_acc];
            float4 v = *(const float4*)&sXV[i][d0];
            a0 = fmaf(p, v.x, a0); a1 = fmaf(p, v.y, a1);
            a2 = fmaf(p, v.z, a2); a3 = fmaf(p, v.w, a3);
        }
        __syncthreads();
    }
    redm[r_st][stripe] = m_st;
    reds[r_st][stripe] = s_st;
    __syncthreads();
    if (tid < 32) {
        float m = -1e30f;
#pragma unroll
        for (int k = 0; k < 8; ++k) m = fmaxf(m, redm[tid][k]);
        float s = 0.f;
#pragma unroll
        for (int k = 0; k < 8; ++k) s += reds[tid][k] * __expf(redm[tid][k] - m);
        M2[blk * 32 + tid] = m;
        S2[blk * 32 + tid] = s;
    }
    *(float4*)&VL[((size_t)blk * 32 + r_acc) * 32 + d0] = make_float4(a0, a1, a2, a3);
}

// ---------------- K4: scatter landmarks + gates + first residual ----------------
__global__ void k_out1(const float* __restrict__ x,
                       const unsigned short* __restrict__ Lb, const unsigned short* __restrict__ XVb,
                       const float* __restrict__ VL, const float* __restrict__ M2, const float* __restrict__ S2,
                       const float* __restrict__ alpha, const float* __restrict__ beta,
                       unsigned short* __restrict__ X2b)
{
    __shared__ float sVL[128][32];
    __shared__ float sP[8][128];
    __shared__ float sM[128], sSi[128], sAB[8];
    int tid = threadIdx.x;
    int tk0 = blockIdx.x * 8;
    int bt = tk0 >> 10;
    for (int k = tid; k < 4096; k += 256) sVL[k >> 5][k & 31] = VL[(size_t)bt * 4096 + k];
    if (tid < 128) { sM[tid] = M2[bt * 128 + tid]; sSi[tid] = 1.f / S2[bt * 128 + tid]; }
    if (tid < 8)   sAB[tid] = (tid < 4) ? sigmoidf_(alpha[tid]) : sigmoidf_(beta[tid - 4]);
    __syncthreads();
    {
        int ti2 = tid >> 5, f4 = (tid & 31) * 4;
        us4 lv = *(const us4*)&Lb[(size_t)(tk0 + ti2) * 128 + f4];
#pragma unroll
        for (int j = 0; j < 4; ++j)
            sP[ti2][f4 + j] = __expf(bu2f(lv[j]) - sM[f4 + j]) * sSi[f4 + j];
    }
    __syncthreads();
    int ti = tid >> 5, quad = tid & 31;
    int h = quad >> 3, d0 = (quad & 7) * 4;
    float a0 = 0, a1 = 0, a2 = 0, a3 = 0;
    int hr0 = h * 32;
#pragma unroll 4
    for (int r = 0; r < 32; ++r) {
        float p = sP[ti][hr0 + r];
        float4 v = *(const float4*)&sVL[hr0 + r][d0];
        a0 = fmaf(p, v.x, a0); a1 = fmaf(p, v.y, a1);
        a2 = fmaf(p, v.z, a2); a3 = fmaf(p, v.w, a3);
    }
    size_t gi = (size_t)(tk0 + ti) * 128 + quad * 4;
    ushort4 xv4 = *(const ushort4*)&XVb[gi];
    float sa = sAB[h], sb = sAB[4 + h];
    float o0 = fmaf(sb, a0, fmaf(sa, bu2f(xv4.x), x[gi + 0]));
    float o1 = fmaf(sb, a1, fmaf(sa, bu2f(xv4.y), x[gi + 1]));
    float o2 = fmaf(sb, a2, fmaf(sa, bu2f(xv4.z), x[gi + 2]));
    float o3 = fmaf(sb, a3, fmaf(sa, bu2f(xv4.w), x[gi + 3]));
    ushort4 pk; pk.x = f2bu(o0); pk.y = f2bu(o1); pk.z = f2bu(o2); pk.w = f2bu(o3);
    *(ushort4*)&X2b[gi] = pk;
}

// ---------------- K6: MFMA FFN + fused rms2 + final residual ----------------
// r6 structure (measured 236 us): block = (b,n), 4 waves, 2 blocks/CU.
// xstage transposed+swizzled; fused rms2; xnf[2][8] in regs (4 MFMA chains in
// phase B); double-buffered gT (1 barrier/iter); a3 prefetch.
// NEW vs r6: oacc pre-initialized with residual+b3 from xstage (epilogue =
// pure store, no global re-read of X2b).
constexpr int XST = 132;                 // xstage row stride (ushorts)
__global__ __launch_bounds__(256, 2) void k_ffn_mfma(
    const unsigned short* __restrict__ X2b, const float* __restrict__ nw,
    const unsigned short* __restrict__ w1b, const float* __restrict__ b1,
    const unsigned short* __restrict__ w2b, const float* __restrict__ b2,
    const unsigned short* __restrict__ w3b, const float* __restrict__ b3,
    float* __restrict__ out)
{
    __shared__ unsigned short smem[18432] __attribute__((aligned(16)));  // 36864 B union
    unsigned short* xstage = smem;           // [128][XST] = 16896 us (prologue)
    unsigned short* gT     = smem;           // [2][128][72] = 18432 us (K-loop)
    __shared__ float sscale[128];

    const int tid  = threadIdx.x;
    const int lane = tid & 63;
    const int wv   = tid >> 6;
    const int lr   = lane & 31;
    const int lhi  = lane >> 5;
    const int blk  = blockIdx.x;
    const int b    = blk >> 10, n = blk & 1023;

    const int mrow = (wv & 1) * 32;     // o-local base (phase B)
    const int fh   = (wv >> 1) * 64;    // f base (phase B)
    const int t0   = wv * 32;           // t-tile base (phase C)

    // ---- stage X2 column-slab into LDS transposed: xstage[f][t ^ swz(f)] ----
    const unsigned short* xg = X2b + ((size_t)(b * Tc) * Nc + n) * 128;
#pragma unroll
    for (int p = 0; p < 8; ++p) {
        int i = p * 256 + tid;
        int t = i >> 4, fg = i & 15;
        us8 v = *(const us8*)(xg + (size_t)t * NF + fg * 8);
        int tt = t ^ ((fg & 7) << 3);
#pragma unroll
        for (int j = 0; j < 8; ++j) xstage[(fg * 8 + j) * XST + tt] = v[j];
    }
    __syncthreads();

    // ---- fused rms2: sum over t of X2^2 per f ----
    {
        int f = tid >> 1, half = tid & 1;
        float ss = 0.f;
#pragma unroll
        for (int kk = 0; kk < 16; ++kk) {
            us4 u = *(const us4*)&xstage[f * XST + half * 64 + kk * 4];
#pragma unroll
            for (int j = 0; j < 4; ++j) { float v = bu2f(u[j]); ss = fmaf(v, v, ss); }
        }
        ss += __shfl_xor(ss, 1);
        if (half == 0) sscale[f] = rsqrtf(ss * (1.f / Tc) + EPSc) * nw[f];
    }
    __syncthreads();

    // ---- build XN B-fragments from LDS (2 f-tiles, 64 VGPR) ----
    bf16x8 xnf[2][8];
#pragma unroll
    for (int ft = 0; ft < 2; ++ft) {
        const int f = fh + ft * 32 + lr;
        const int swz = ((f >> 3) & 7) << 3;
        const float scale = sscale[f];
#pragma unroll
        for (int s = 0; s < 8; ++s) {
            int tb = (s * 16 + lhi * 8) ^ swz;
            us4 u0 = *(const us4*)&xstage[f * XST + tb];
            us4 u1 = *(const us4*)&xstage[f * XST + tb + 4];
            bf16x8 v;
#pragma unroll
            for (int j = 0; j < 4; ++j) {
                v[j]     = (__bf16)(bu2f(u0[j]) * scale);
                v[j + 4] = (__bf16)(bu2f(u1[j]) * scale);
            }
            xnf[ft][s] = v;
        }
    }

    // ---- oacc init: residual + b3, raw X2 from xstage ----
    f32x16 oacc[4];
#pragma unroll
    for (int c = 0; c < 4; ++c) {
        const int f = c * 32 + lr;
        const int swz = ((f >> 3) & 7) << 3;
#pragma unroll
        for (int q = 0; q < 4; ++q) {
            const int tb = t0 + 8 * q + 4 * lhi;
            us4 u = *(const us4*)&xstage[f * XST + (tb ^ swz)];
#pragma unroll
            for (int e = 0; e < 4; ++e)
                oacc[c][q * 4 + e] = bu2f(u[e]) + b3[tb + e];
        }
    }
    __syncthreads();    // xstage dead; gT may now be written

    const unsigned short* w1r = w1b + (size_t)(mrow + lr) * 128 + lhi * 8;
    const unsigned short* w2r = w2b + (size_t)(mrow + lr) * 128 + lhi * 8;
    const unsigned short* w3r = w3b + (size_t)(t0 + lr) * 512 + lhi * 8;

    int d = 0;
    for (int oc = 0; oc < 512; oc += 64) {
        // prefetch w3 fragments for this chunk (consumed after the barrier)
        bf16x8 a3[4];
        const unsigned short* pw3 = w3r + oc;
#pragma unroll
        for (int s = 0; s < 4; ++s) a3[s] = *(const bf16x8*)(pw3 + s * 16);

        // ---------- phase B: H1/H2 for this o-chunk (4 independent chains) ----------
        f32x16 h1a = zero16(), h1b = zero16(), h2a = zero16(), h2b = zero16();
        const unsigned short* pw1 = w1r + (size_t)oc * 128;
        const unsigned short* pw2 = w2r + (size_t)oc * 128;
#pragma unroll
        for (int s = 0; s < 8; ++s) {
            bf16x8 a1 = *(const bf16x8*)(pw1 + s * 16);
            bf16x8 a2 = *(const bf16x8*)(pw2 + s * 16);
            h1a = __builtin_amdgcn_mfma_f32_32x32x16_bf16(a1, xnf[0][s], h1a, 0, 0, 0);
            h1b = __builtin_amdgcn_mfma_f32_32x32x16_bf16(a1, xnf[1][s], h1b, 0, 0, 0);
            h2a = __builtin_amdgcn_mfma_f32_32x32x16_bf16(a2, xnf[0][s], h2a, 0, 0, 0);
            h2b = __builtin_amdgcn_mfma_f32_32x32x16_bf16(a2, xnf[1][s], h2b, 0, 0, 0);
        }
        // g = silu(h1 + b1) * (h2 + b2) -> gT[d]
        unsigned short* gTd = gT + d * 9216;
#pragma unroll
        for (int ft = 0; ft < 2; ++ft) {
            const int fcol = fh + ft * 32 + lr;
#pragma unroll
            for (int q = 0; q < 4; ++q) {
                ushort4 pk;
#pragma unroll
                for (int e = 0; e < 4; ++e) {
                    const int r = q * 4 + e;
                    const int orow = oc + mrow + e + 8 * q + 4 * lhi;
                    float z   = (ft ? h1b[r] : h1a[r]) + b1[orow];
                    float h2v = (ft ? h2b[r] : h2a[r]) + b2[orow];
                    float g   = z * sigmoidf_(z) * h2v;
                    unsigned short gb = f2bu(g);
                    if (e == 0) pk.x = gb; else if (e == 1) pk.y = gb;
                    else if (e == 2) pk.z = gb; else pk.w = gb;
                }
                const int o_l = mrow + 8 * q + 4 * lhi;
                *(ushort4*)&gTd[fcol * 72 + o_l] = pk;
            }
        }
        __syncthreads();
        // ---------- phase C: OUT += W3[:, oc..oc+63] * G ----------
#pragma unroll
        for (int s = 0; s < 4; ++s) {
#pragma unroll
            for (int c = 0; c < 4; ++c) {
                bf16x8 bg = *(const bf16x8*)&gTd[(c * 32 + lr) * 72 + s * 16 + lhi * 8];
                oacc[c] = __builtin_amdgcn_mfma_f32_32x32x16_bf16(a3[s], bg, oacc[c], 0, 0, 0);
            }
        }
        d ^= 1;   // next phase B writes the other buffer; no second barrier needed
    }

    // ---------- epilogue: out = oacc (residual+b3 already folded in) ----------
#pragma unroll
    for (int r = 0; r < 16; ++r) {
        const int t = t0 + (r & 3) + 8 * (r >> 2) + 4 * lhi;
        const size_t rowbase = ((size_t)(b * Tc + t) * Nc + n) * 128;
#pragma unroll
        for (int c = 0; c < 4; ++c) {
            out[rowbase + c * 32 + lr] = oacc[c][r];
        }
    }
}

extern "C" void kernel_launch(void* const* d_in, const int* in_sizes, int n_in,
                              void* d_out, int out_size, void* d_ws, size_t ws_size,
                              hipStream_t stream) {
    const float* x      = (const float*)d_in[0];
    const float* norm_w = (const float*)d_in[1];
    const float* q_w    = (const float*)d_in[2];
    const float* q_b    = (const float*)d_in[3];
    const float* key_p  = (const float*)d_in[4];
    const float* v_w    = (const float*)d_in[5];
    const float* v_b    = (const float*)d_in[6];
    const float* alpha  = (const float*)d_in[7];
    const float* beta   = (const float*)d_in[8];
    const float* w1     = (const float*)d_in[9];
    const float* b1     = (const float*)d_in[10];
    const float* w2     = (const float*)d_in[11];
    const float* b2     = (const float*)d_in[12];
    const float* w3     = (const float*)d_in[13];
    const float* b3     = (const float*)d_in[14];
    float* out = (float*)d_out;

    char* ws = (char*)d_ws;
    float* inv1 = (float*)ws;                                    // 262144 f
    float* inv2 = inv1 + (size_t)Bc * NF;                        // 262144 f (spare)
    float* VLp  = inv2 + (size_t)Bc * NF;                        // 1048576 f
    float* M2p  = VLp + (size_t)Bc * Tc * Hc * Rc * Dc;          // 32768 f
    float* S2p  = M2p + (size_t)Bc * Tc * Hc * Rc;               // 32768 f
    unsigned short* Lb  = (unsigned short*)(S2p + (size_t)Bc * Tc * Hc * Rc);
    unsigned short* XVb = Lb  + (size_t)TOK * 128;
    unsigned short* X2b = XVb + (size_t)TOK * 128;               // total ~198.3 MiB

    unsigned short* Wcat = (unsigned short*)VLp;                 // 32768 us
    float* bias256 = VLp + 16384;

    unsigned short* w1bf = Lb;
    unsigned short* w2bf = Lb + 65536;
    unsigned short* w3bf = Lb + 131072;

    k_rms_f32 <<<Bc * NF / 256, 256, 0, stream>>>(x, inv1);
    k_qk      <<<68,            256, 0, stream>>>(q_w, q_b, key_p, v_b, v_w, Wcat, bias256);
    k_projm   <<<TOK / 128,     256, 0, stream>>>(x, inv1, norm_w, Wcat, bias256, Lb, XVb);
    k_land    <<<Bc * Tc * Hc,  256, 0, stream>>>(Lb, XVb, VLp, M2p, S2p);
    k_out1    <<<TOK / 8,       256, 0, stream>>>(x, Lb, XVb, VLp, M2p, S2p, alpha, beta, X2b);
    k_cvt3    <<<768,           256, 0, stream>>>(w1, w2, w3, w1bf);
    k_ffn_mfma<<<Bc * Nc,       256, 0, stream>>>(X2b, norm_w, w1bf, b1, w2bf, b2, w3bf, b3, out);
}

// Round 15
// 525.834 us; speedup vs baseline: 1.3908x; 1.0177x over previous
//
#include <hip/hip_runtime.h>

#define DEV static __device__ __forceinline__

constexpr int Bc = 2, Tc = 128, Nc = 1024, Fc = 128, Hc = 4, Rc = 32, Dc = 32;
constexpr int NF  = Nc * Fc;        // 131072 = 2^17
constexpr int TOK = Bc * Tc * Nc;   // 262144
constexpr float EPSc = 1e-6f;
constexpr float RSD  = 0.17677669529663687f;  // 1/sqrt(32)

typedef __bf16 bf16x8 __attribute__((ext_vector_type(8)));
typedef float  f32x16 __attribute__((ext_vector_type(16)));
typedef unsigned short us8 __attribute__((ext_vector_type(8)));
typedef unsigned short us4 __attribute__((ext_vector_type(4)));

DEV unsigned short f2bu(float f) {              // fp32 -> bf16 (RNE)
    unsigned u = __builtin_bit_cast(unsigned, f);
    u += 0x7fffu + ((u >> 16) & 1u);
    return (unsigned short)(u >> 16);
}
DEV float bu2f(unsigned short s) {
    return __builtin_bit_cast(float, ((unsigned)s) << 16);
}
DEV float sigmoidf_(float z) { return 1.f / (1.f + __expf(-z)); }
DEV f32x16 zero16() { f32x16 z;
#pragma unroll
    for (int i = 0; i < 16; i++) z[i] = 0.f;
    return z; }

// ---------------- K_prep: rms1 + QK-fold + all weight cvt (one launch) ----------------
// blocks 0..1023   : inv1 (rmsnorm-over-t scales for x)
// blocks 1024..1027: Wcat rows 0..127 = QK fold, + bias
// blocks 1028..1091: Wcat rows 128..255 = bf16(v_w)
// blocks 1092..1859: wbf = bf16(w1|w2|w3)
__global__ void k_prep(const float* __restrict__ x, float* __restrict__ inv,
                       const float* __restrict__ q_w, const float* __restrict__ q_b,
                       const float* __restrict__ key_p, const float* __restrict__ v_b,
                       const float* __restrict__ v_w,
                       unsigned short* __restrict__ Wcat, float* __restrict__ bias,
                       const float* __restrict__ w1, const float* __restrict__ w2,
                       const float* __restrict__ w3, unsigned short* __restrict__ wbf)
{
    __shared__ float sqw[32][128];
    __shared__ float skp[32][32];
    const int blk = blockIdx.x, tid = threadIdx.x;
    if (blk < 1024) {                       // ---- rms1 ----
        int j = blk * 256 + tid;            // j = b*NF + p
        int b = j >> 17;
        int p = j & (NF - 1);
        const float* px = x + (size_t)b * Tc * NF + p;
        float s = 0.f;
#pragma unroll 8
        for (int t = 0; t < Tc; ++t) { float v = px[(size_t)t * NF]; s = fmaf(v, v, s); }
        inv[j] = rsqrtf(s * (1.f / Tc) + EPSc);
        return;
    }
    if (blk < 1028) {                       // ---- QK fold ----
        int h = blk - 1024;
        for (int i = tid; i < 4096; i += 256) {
            int d = i >> 7, c = i & 127;
            sqw[d][c] = q_w[(size_t)(h * 32 + d) * 128 + c];
        }
        for (int i = tid; i < 1024; i += 256) {
            int r = i >> 5, d = i & 31;
            skp[r][d] = key_p[(size_t)(r * 4 + h) * 32 + d] * RSD;
        }
        __syncthreads();
        int r = tid >> 3;
        int c0 = (tid & 7) * 16;
        for (int cc = 0; cc < 16; ++cc) {
            int c = c0 + cc;
            float s = 0.f;
#pragma unroll
            for (int d = 0; d < 32; ++d) s = fmaf(sqw[d][c], skp[r][d], s);
            Wcat[(size_t)(h * 32 + r) * 128 + c] = f2bu(s);
        }
        if (tid < 32) {
            float s = 0.f;
#pragma unroll
            for (int d = 0; d < 32; ++d) s = fmaf(q_b[h * 32 + d], skp[tid][d], s);
            bias[h * 32 + tid] = s;
        }
        if (h == 0 && tid >= 64 && tid < 192) bias[128 + tid - 64] = v_b[tid - 64];
        return;
    }
    if (blk < 1092) {                       // ---- v_w cvt ----
        int i = (blk - 1028) * 256 + tid;   // 0..16383
        Wcat[16384 + i] = f2bu(v_w[i]);
        return;
    }
    {                                       // ---- w1/w2/w3 cvt ----
        int i = (blk - 1092) * 256 + tid;   // 0..196607
        float v;
        if (i < 65536)       v = w1[i];
        else if (i < 131072) v = w2[i - 65536];
        else                 v = w3[i - 131072];
        wbf[i] = f2bu(v);
    }
}

// ---------------- K2: MFMA projection: [L ; XV] = XN @ Wcat^T + bias ----------------
__global__ __launch_bounds__(256, 4) void k_projm(
    const float* __restrict__ x, const float* __restrict__ inv1, const float* __restrict__ nw,
    const unsigned short* __restrict__ Wcat, const float* __restrict__ bias,
    unsigned short* __restrict__ Lb, unsigned short* __restrict__ XVb)
{
    const int tid = threadIdx.x, lane = tid & 63, wv = tid >> 6;
    const int lr = lane & 31, lhi = lane >> 5;
    const int tokb = blockIdx.x * 128 + wv * 32;
    const int tok = tokb + lr;
    const int b = tok >> 17, n = tok & 1023;
    const float* px = x + (size_t)tok * 128;
    const float* pi = inv1 + (size_t)b * NF + n * 128;

    bf16x8 af[8];
#pragma unroll
    for (int s = 0; s < 8; ++s) {
        const int c0 = s * 16 + lhi * 8;
        float4 xa = *(const float4*)(px + c0);
        float4 xb = *(const float4*)(px + c0 + 4);
        float4 ia = *(const float4*)(pi + c0);
        float4 ib = *(const float4*)(pi + c0 + 4);
        float4 na = *(const float4*)(nw + c0);
        float4 nb = *(const float4*)(nw + c0 + 4);
        bf16x8 v;
        v[0] = (__bf16)(xa.x * ia.x * na.x);
        v[1] = (__bf16)(xa.y * ia.y * na.y);
        v[2] = (__bf16)(xa.z * ia.z * na.z);
        v[3] = (__bf16)(xa.w * ia.w * na.w);
        v[4] = (__bf16)(xb.x * ib.x * nb.x);
        v[5] = (__bf16)(xb.y * ib.y * nb.y);
        v[6] = (__bf16)(xb.z * ib.z * nb.z);
        v[7] = (__bf16)(xb.w * ib.w * nb.w);
        af[s] = v;
    }

#pragma unroll
    for (int ot = 0; ot < 8; ++ot) {
        const unsigned short* pw = Wcat + (size_t)(ot * 32 + lr) * 128 + lhi * 8;
        f32x16 acc = zero16();
#pragma unroll
        for (int s = 0; s < 8; ++s) {
            bf16x8 bw = *(const bf16x8*)(pw + s * 16);
            acc = __builtin_amdgcn_mfma_f32_32x32x16_bf16(af[s], bw, acc, 0, 0, 0);
        }
        const int o = ot * 32 + lr;
        const float bv = bias[o];
        unsigned short* dst = (ot < 4) ? Lb : XVb;
        const int oo = (ot < 4) ? o : o - 128;
#pragma unroll
        for (int r = 0; r < 16; ++r) {
            const int trow = tokb + (r & 3) + 8 * (r >> 2) + 4 * lhi;
            dst[(size_t)trow * 128 + oo] = f2bu(acc[r] + bv);
        }
    }
}

// ---------------- K3: landmark aggregation + n-softmax stats (parallel, vec loads) ----------------
__global__ __launch_bounds__(256, 4) void k_land(
    const unsigned short* __restrict__ Lb, const unsigned short* __restrict__ XVb,
    float* __restrict__ VL, float* __restrict__ M2, float* __restrict__ S2)
{
    __shared__ float sL [64][34];
    __shared__ float sXV[64][36];
    __shared__ float redm[32][8];
    __shared__ float reds[32][8];
    int tid = threadIdx.x;
    int blk = blockIdx.x;               // bt*4 + h
    int h = blk & 3; int bt = blk >> 2;
    size_t base = (size_t)bt * Nc * 128 + h * 32;
    const int li = tid >> 2, c8 = (tid & 3) * 8;      // load mapping (us8)
    const int r_st = tid & 31, stripe = tid >> 5;     // stats mapping
    const int ti = tid >> 2, sub = tid & 3;           // p1 mapping
    const int r_acc = tid >> 3, d0 = (tid & 7) * 4;   // VL mapping
    float m_st = -1e30f, s_st = 0.f;
    float a0 = 0, a1 = 0, a2 = 0, a3 = 0;
    for (int n0 = 0; n0 < Nc; n0 += 64) {
        {
            size_t g = base + (size_t)(n0 + li) * 128 + c8;
            us8 vL = *(const us8*)(Lb + g);
            us8 vX = *(const us8*)(XVb + g);
#pragma unroll
            for (int j = 0; j < 8; ++j) {
                sL [li][c8 + j] = bu2f(vL[j]);
                sXV[li][c8 + j] = bu2f(vX[j]);
            }
        }
        __syncthreads();
#pragma unroll
        for (int i8 = 0; i8 < 8; ++i8) {
            float v = sL[stripe * 8 + i8][r_st];
            float mn = fmaxf(m_st, v);
            s_st = s_st * __expf(m_st - mn) + __expf(v - mn);
            m_st = mn;
        }
        float e[8];
        float mx = -1e30f;
#pragma unroll
        for (int j = 0; j < 8; ++j) mx = fmaxf(mx, sL[ti][sub * 8 + j]);
        mx = fmaxf(mx, __shfl_xor(mx, 1));
        mx = fmaxf(mx, __shfl_xor(mx, 2));
        float sm = 0.f;
#pragma unroll
        for (int j = 0; j < 8; ++j) { e[j] = __expf(sL[ti][sub * 8 + j] - mx); sm += e[j]; }
        sm += __shfl_xor(sm, 1);
        sm += __shfl_xor(sm, 2);
        float iv = 1.f / sm;
        __syncthreads();                 // all reads of sL done
#pragma unroll
        for (int j = 0; j < 8; ++j) sL[ti][sub * 8 + j] = e[j] * iv;
        __syncthreads();
#pragma unroll 2
        for (int i = 0; i < 64; ++i) {
            float p = sL[i][r_acc];
            float4 v = *(const float4*)&sXV[i][d0];
            a0 = fmaf(p, v.x, a0); a1 = fmaf(p, v.y, a1);
            a2 = fmaf(p, v.z, a2); a3 = fmaf(p, v.w, a3);
        }
        __syncthreads();
    }
    redm[r_st][stripe] = m_st;
    reds[r_st][stripe] = s_st;
    __syncthreads();
    if (tid < 32) {
        float m = -1e30f;
#pragma unroll
        for (int k = 0; k < 8; ++k) m = fmaxf(m, redm[tid][k]);
        float s = 0.f;
#pragma unroll
        for (int k = 0; k < 8; ++k) s += reds[tid][k] * __expf(redm[tid][k] - m);
        M2[blk * 32 + tid] = m;
        S2[blk * 32 + tid] = s;
    }
    *(float4*)&VL[((size_t)blk * 32 + r_acc) * 32 + d0] = make_float4(a0, a1, a2, a3);
}

// ---------------- K4: scatter landmarks + gates + first residual (32 tok/block) ----------------
__global__ __launch_bounds__(256) void k_out1(
    const float* __restrict__ x,
    const unsigned short* __restrict__ Lb, const unsigned short* __restrict__ XVb,
    const float* __restrict__ VL, const float* __restrict__ M2, const float* __restrict__ S2,
    const float* __restrict__ alpha, const float* __restrict__ beta,
    unsigned short* __restrict__ X2b)
{
    __shared__ float sVL[128][32];
    __shared__ float sP[8][128];
    __shared__ float sM[128], sSi[128], sAB[8];
    int tid = threadIdx.x;
    int tk00 = blockIdx.x * 32;          // 32 tokens, all same bt (1024 | 32)
    int bt = tk00 >> 10;
    for (int k = tid; k < 4096; k += 256) sVL[k >> 5][k & 31] = VL[(size_t)bt * 4096 + k];
    if (tid < 128) { sM[tid] = M2[bt * 128 + tid]; sSi[tid] = 1.f / S2[bt * 128 + tid]; }
    if (tid < 8)   sAB[tid] = (tid < 4) ? sigmoidf_(alpha[tid]) : sigmoidf_(beta[tid - 4]);
    __syncthreads();
    const int ti = tid >> 5, quad = tid & 31;
    const int h = quad >> 3, d0 = (quad & 7) * 4;
    const int hr0 = h * 32;
    const int f4 = (tid & 31) * 4;
    const float sa = sAB[h], sb = sAB[4 + h];
    for (int tg = 0; tg < 4; ++tg) {
        const int tk0 = tk00 + tg * 8;
        {
            us4 lv = *(const us4*)&Lb[(size_t)(tk0 + ti) * 128 + f4];
#pragma unroll
            for (int j = 0; j < 4; ++j)
                sP[ti][f4 + j] = __expf(bu2f(lv[j]) - sM[f4 + j]) * sSi[f4 + j];
        }
        __syncthreads();
        float a0 = 0, a1 = 0, a2 = 0, a3 = 0;
#pragma unroll 4
        for (int r = 0; r < 32; ++r) {
            float p = sP[ti][hr0 + r];
            float4 v = *(const float4*)&sVL[hr0 + r][d0];
            a0 = fmaf(p, v.x, a0); a1 = fmaf(p, v.y, a1);
            a2 = fmaf(p, v.z, a2); a3 = fmaf(p, v.w, a3);
        }
        size_t gi = (size_t)(tk0 + ti) * 128 + quad * 4;
        ushort4 xv4 = *(const ushort4*)&XVb[gi];
        float o0 = fmaf(sb, a0, fmaf(sa, bu2f(xv4.x), x[gi + 0]));
        float o1 = fmaf(sb, a1, fmaf(sa, bu2f(xv4.y), x[gi + 1]));
        float o2 = fmaf(sb, a2, fmaf(sa, bu2f(xv4.z), x[gi + 2]));
        float o3 = fmaf(sb, a3, fmaf(sa, bu2f(xv4.w), x[gi + 3]));
        ushort4 pk; pk.x = f2bu(o0); pk.y = f2bu(o1); pk.z = f2bu(o2); pk.w = f2bu(o3);
        *(ushort4*)&X2b[gi] = pk;
        __syncthreads();
    }
}

// ---------------- K6: MFMA FFN + fused rms2 + final residual ----------------
// r6 structure (measured ~234 us): block = (b,n), 4 waves, 2 blocks/CU.
constexpr int XST = 132;                 // xstage row stride (ushorts)
__global__ __launch_bounds__(256, 2) void k_ffn_mfma(
    const unsigned short* __restrict__ X2b, const float* __restrict__ nw,
    const unsigned short* __restrict__ w1b, const float* __restrict__ b1,
    const unsigned short* __restrict__ w2b, const float* __restrict__ b2,
    const unsigned short* __restrict__ w3b, const float* __restrict__ b3,
    float* __restrict__ out)
{
    __shared__ unsigned short smem[18432] __attribute__((aligned(16)));  // 36864 B union
    unsigned short* xstage = smem;           // [128][XST] = 16896 us (prologue)
    unsigned short* gT     = smem;           // [2][128][72] = 18432 us (K-loop)
    __shared__ float sscale[128];

    const int tid  = threadIdx.x;
    const int lane = tid & 63;
    const int wv   = tid >> 6;
    const int lr   = lane & 31;
    const int lhi  = lane >> 5;
    const int blk  = blockIdx.x;
    const int b    = blk >> 10, n = blk & 1023;

    const int mrow = (wv & 1) * 32;     // o-local base (phase B)
    const int fh   = (wv >> 1) * 64;    // f base (phase B)
    const int t0   = wv * 32;           // t-tile base (phase C)

    // ---- stage X2 column-slab into LDS transposed: xstage[f][t ^ swz(f)] ----
    const unsigned short* xg = X2b + ((size_t)(b * Tc) * Nc + n) * 128;
#pragma unroll
    for (int p = 0; p < 8; ++p) {
        int i = p * 256 + tid;
        int t = i >> 4, fg = i & 15;
        us8 v = *(const us8*)(xg + (size_t)t * NF + fg * 8);
        int tt = t ^ ((fg & 7) << 3);
#pragma unroll
        for (int j = 0; j < 8; ++j) xstage[(fg * 8 + j) * XST + tt] = v[j];
    }
    __syncthreads();

    // ---- fused rms2: sum over t of X2^2 per f ----
    {
        int f = tid >> 1, half = tid & 1;
        float ss = 0.f;
#pragma unroll
        for (int kk = 0; kk < 16; ++kk) {
            us4 u = *(const us4*)&xstage[f * XST + half * 64 + kk * 4];
#pragma unroll
            for (int j = 0; j < 4; ++j) { float v = bu2f(u[j]); ss = fmaf(v, v, ss); }
        }
        ss += __shfl_xor(ss, 1);
        if (half == 0) sscale[f] = rsqrtf(ss * (1.f / Tc) + EPSc) * nw[f];
    }
    __syncthreads();

    // ---- build XN B-fragments from LDS (2 f-tiles, 64 VGPR) ----
    bf16x8 xnf[2][8];
#pragma unroll
    for (int ft = 0; ft < 2; ++ft) {
        const int f = fh + ft * 32 + lr;
        const int swz = ((f >> 3) & 7) << 3;
        const float scale = sscale[f];
#pragma unroll
        for (int s = 0; s < 8; ++s) {
            int tb = (s * 16 + lhi * 8) ^ swz;
            us4 u0 = *(const us4*)&xstage[f * XST + tb];
            us4 u1 = *(const us4*)&xstage[f * XST + tb + 4];
            bf16x8 v;
#pragma unroll
            for (int j = 0; j < 4; ++j) {
                v[j]     = (__bf16)(bu2f(u0[j]) * scale);
                v[j + 4] = (__bf16)(bu2f(u1[j]) * scale);
            }
            xnf[ft][s] = v;
        }
    }

    // ---- oacc init: residual + b3, raw X2 from xstage ----
    f32x16 oacc[4];
#pragma unroll
    for (int c = 0; c < 4; ++c) {
        const int f = c * 32 + lr;
        const int swz = ((f >> 3) & 7) << 3;
#pragma unroll
        for (int q = 0; q < 4; ++q) {
            const int tb = t0 + 8 * q + 4 * lhi;
            us4 u = *(const us4*)&xstage[f * XST + (tb ^ swz)];
#pragma unroll
            for (int e = 0; e < 4; ++e)
                oacc[c][q * 4 + e] = bu2f(u[e]) + b3[tb + e];
        }
    }
    __syncthreads();    // xstage dead; gT may now be written

    const unsigned short* w1r = w1b + (size_t)(mrow + lr) * 128 + lhi * 8;
    const unsigned short* w2r = w2b + (size_t)(mrow + lr) * 128 + lhi * 8;
    const unsigned short* w3r = w3b + (size_t)(t0 + lr) * 512 + lhi * 8;

    int d = 0;
    for (int oc = 0; oc < 512; oc += 64) {
        // prefetch w3 fragments for this chunk (consumed after the barrier)
        bf16x8 a3[4];
        const unsigned short* pw3 = w3r + oc;
#pragma unroll
        for (int s = 0; s < 4; ++s) a3[s] = *(const bf16x8*)(pw3 + s * 16);

        // ---------- phase B: H1/H2 for this o-chunk (4 independent chains) ----------
        f32x16 h1a = zero16(), h1b = zero16(), h2a = zero16(), h2b = zero16();
        const unsigned short* pw1 = w1r + (size_t)oc * 128;
        const unsigned short* pw2 = w2r + (size_t)oc * 128;
#pragma unroll
        for (int s = 0; s < 8; ++s) {
            bf16x8 a1 = *(const bf16x8*)(pw1 + s * 16);
            bf16x8 a2 = *(const bf16x8*)(pw2 + s * 16);
            h1a = __builtin_amdgcn_mfma_f32_32x32x16_bf16(a1, xnf[0][s], h1a, 0, 0, 0);
            h1b = __builtin_amdgcn_mfma_f32_32x32x16_bf16(a1, xnf[1][s], h1b, 0, 0, 0);
            h2a = __builtin_amdgcn_mfma_f32_32x32x16_bf16(a2, xnf[0][s], h2a, 0, 0, 0);
            h2b = __builtin_amdgcn_mfma_f32_32x32x16_bf16(a2, xnf[1][s], h2b, 0, 0, 0);
        }
        // g = silu(h1 + b1) * (h2 + b2) -> gT[d]
        unsigned short* gTd = gT + d * 9216;
#pragma unroll
        for (int ft = 0; ft < 2; ++ft) {
            const int fcol = fh + ft * 32 + lr;
#pragma unroll
            for (int q = 0; q < 4; ++q) {
                ushort4 pk;
#pragma unroll
                for (int e = 0; e < 4; ++e) {
                    const int r = q * 4 + e;
                    const int orow = oc + mrow + e + 8 * q + 4 * lhi;
                    float z   = (ft ? h1b[r] : h1a[r]) + b1[orow];
                    float h2v = (ft ? h2b[r] : h2a[r]) + b2[orow];
                    float g   = z * sigmoidf_(z) * h2v;
                    unsigned short gb = f2bu(g);
                    if (e == 0) pk.x = gb; else if (e == 1) pk.y = gb;
                    else if (e == 2) pk.z = gb; else pk.w = gb;
                }
                const int o_l = mrow + 8 * q + 4 * lhi;
                *(ushort4*)&gTd[fcol * 72 + o_l] = pk;
            }
        }
        __syncthreads();
        // ---------- phase C: OUT += W3[:, oc..oc+63] * G ----------
#pragma unroll
        for (int s = 0; s < 4; ++s) {
#pragma unroll
            for (int c = 0; c < 4; ++c) {
                bf16x8 bg = *(const bf16x8*)&gTd[(c * 32 + lr) * 72 + s * 16 + lhi * 8];
                oacc[c] = __builtin_amdgcn_mfma_f32_32x32x16_bf16(a3[s], bg, oacc[c], 0, 0, 0);
            }
        }
        d ^= 1;   // next phase B writes the other buffer; no second barrier needed
    }

    // ---------- epilogue: out = oacc (residual+b3 already folded in) ----------
#pragma unroll
    for (int r = 0; r < 16; ++r) {
        const int t = t0 + (r & 3) + 8 * (r >> 2) + 4 * lhi;
        const size_t rowbase = ((size_t)(b * Tc + t) * Nc + n) * 128;
#pragma unroll
        for (int c = 0; c < 4; ++c) {
            out[rowbase + c * 32 + lr] = oacc[c][r];
        }
    }
}

extern "C" void kernel_launch(void* const* d_in, const int* in_sizes, int n_in,
                              void* d_out, int out_size, void* d_ws, size_t ws_size,
                              hipStream_t stream) {
    const float* x      = (const float*)d_in[0];
    const float* norm_w = (const float*)d_in[1];
    const float* q_w    = (const float*)d_in[2];
    const float* q_b    = (const float*)d_in[3];
    const float* key_p  = (const float*)d_in[4];
    const float* v_w    = (const float*)d_in[5];
    const float* v_b    = (const float*)d_in[6];
    const float* alpha  = (const float*)d_in[7];
    const float* beta   = (const float*)d_in[8];
    const float* w1     = (const float*)d_in[9];
    const float* b1     = (const float*)d_in[10];
    const float* w2     = (const float*)d_in[11];
    const float* b2     = (const float*)d_in[12];
    const float* w3     = (const float*)d_in[13];
    const float* b3     = (const float*)d_in[14];
    float* out = (float*)d_out;

    char* ws = (char*)d_ws;
    float* inv1 = (float*)ws;                                    // 262144 f
    float* inv2 = inv1 + (size_t)Bc * NF;                        // 262144 f (holds wbf now)
    float* VLp  = inv2 + (size_t)Bc * NF;                        // 1048576 f
    float* M2p  = VLp + (size_t)Bc * Tc * Hc * Rc * Dc;          // 32768 f
    float* S2p  = M2p + (size_t)Bc * Tc * Hc * Rc;               // 32768 f
    unsigned short* Lb  = (unsigned short*)(S2p + (size_t)Bc * Tc * Hc * Rc);
    unsigned short* XVb = Lb  + (size_t)TOK * 128;
    unsigned short* X2b = XVb + (size_t)TOK * 128;               // total ~198.3 MiB

    // Wcat (256x128 bf16) + bias (256 f) alias the VLp region (VL written later by k_land)
    unsigned short* Wcat = (unsigned short*)VLp;                 // 32768 us
    float* bias256 = VLp + 16384;

    // bf16 weight copies live in the spare inv2 region (384 KB < 1 MB)
    unsigned short* w1bf = (unsigned short*)inv2;
    unsigned short* w2bf = w1bf + 65536;
    unsigned short* w3bf = w1bf + 131072;

    k_prep    <<<1860,          256, 0, stream>>>(x, inv1, q_w, q_b, key_p, v_b, v_w,
                                                  Wcat, bias256, w1, w2, w3, w1bf);
    k_projm   <<<TOK / 128,     256, 0, stream>>>(x, inv1, norm_w, Wcat, bias256, Lb, XVb);
    k_land    <<<Bc * Tc * Hc,  256, 0, stream>>>(Lb, XVb, VLp, M2p, S2p);
    k_out1    <<<TOK / 32,      256, 0, stream>>>(x, Lb, XVb, VLp, M2p, S2p, alpha, beta, X2b);
    k_ffn_mfma<<<Bc * Nc,       256, 0, stream>>>(X2b, norm_w, w1bf, b1, w2bf, b2, w3bf, b3, out);
}

// Round 18
// 491.938 us; speedup vs baseline: 1.4866x; 1.0689x over previous
//
#include <hip/hip_runtime.h>

#define DEV static __device__ __forceinline__

constexpr int Bc = 2, Tc = 128, Nc = 1024, Fc = 128, Hc = 4, Rc = 32, Dc = 32;
constexpr int NF  = Nc * Fc;        // 131072 = 2^17
constexpr int TOK = Bc * Tc * Nc;   // 262144
constexpr float EPSc = 1e-6f;
constexpr float RSD  = 0.17677669529663687f;  // 1/sqrt(32)

typedef __bf16 bf16x8 __attribute__((ext_vector_type(8)));
typedef float  f32x16 __attribute__((ext_vector_type(16)));
typedef unsigned short us8 __attribute__((ext_vector_type(8)));
typedef unsigned short us4 __attribute__((ext_vector_type(4)));

DEV unsigned short f2bu(float f) {              // fp32 -> bf16 (RNE)
    unsigned u = __builtin_bit_cast(unsigned, f);
    u += 0x7fffu + ((u >> 16) & 1u);
    return (unsigned short)(u >> 16);
}
DEV float bu2f(unsigned short s) {
    return __builtin_bit_cast(float, ((unsigned)s) << 16);
}
DEV float sigmoidf_(float z) { return 1.f / (1.f + __expf(-z)); }
DEV f32x16 zero16() { f32x16 z;
#pragma unroll
    for (int i = 0; i < 16; i++) z[i] = 0.f;
    return z; }

// ---------------- K_prep: QK-fold + all weight cvt (one launch, no rms now) ----------------
// blocks 0..3  : Wcat rows 0..127 = QK fold, + bias
// blocks 4..67 : Wcat rows 128..255 = bf16(v_w)
// blocks 68..835: wbf = bf16(w1|w2|w3)
__global__ void k_prep(const float* __restrict__ q_w, const float* __restrict__ q_b,
                       const float* __restrict__ key_p, const float* __restrict__ v_b,
                       const float* __restrict__ v_w,
                       unsigned short* __restrict__ Wcat, float* __restrict__ bias,
                       const float* __restrict__ w1, const float* __restrict__ w2,
                       const float* __restrict__ w3, unsigned short* __restrict__ wbf)
{
    __shared__ float sqw[32][128];
    __shared__ float skp[32][32];
    const int blk = blockIdx.x, tid = threadIdx.x;
    if (blk < 4) {                          // ---- QK fold ----
        int h = blk;
        for (int i = tid; i < 4096; i += 256) {
            int d = i >> 7, c = i & 127;
            sqw[d][c] = q_w[(size_t)(h * 32 + d) * 128 + c];
        }
        for (int i = tid; i < 1024; i += 256) {
            int r = i >> 5, d = i & 31;
            skp[r][d] = key_p[(size_t)(r * 4 + h) * 32 + d] * RSD;
        }
        __syncthreads();
        int r = tid >> 3;
        int c0 = (tid & 7) * 16;
        for (int cc = 0; cc < 16; ++cc) {
            int c = c0 + cc;
            float s = 0.f;
#pragma unroll
            for (int d = 0; d < 32; ++d) s = fmaf(sqw[d][c], skp[r][d], s);
            Wcat[(size_t)(h * 32 + r) * 128 + c] = f2bu(s);
        }
        if (tid < 32) {
            float s = 0.f;
#pragma unroll
            for (int d = 0; d < 32; ++d) s = fmaf(q_b[h * 32 + d], skp[tid][d], s);
            bias[h * 32 + tid] = s;
        }
        if (h == 0 && tid >= 64 && tid < 192) bias[128 + tid - 64] = v_b[tid - 64];
        return;
    }
    if (blk < 68) {                         // ---- v_w cvt ----
        int i = (blk - 4) * 256 + tid;      // 0..16383
        Wcat[16384 + i] = f2bu(v_w[i]);
        return;
    }
    {                                       // ---- w1/w2/w3 cvt ----
        int i = (blk - 68) * 256 + tid;     // 0..196607
        float v;
        if (i < 65536)       v = w1[i];
        else if (i < 131072) v = w2[i - 65536];
        else                 v = w3[i - 131072];
        wbf[i] = f2bu(v);
    }
}

// ---------------- K2: MFMA projection + fused rms1: [L ; XV] = XN @ Wcat^T + bias ----------------
// block = (b,n): 128 t-tokens of one column. x slab staged fp32 in LDS
// transposed [c][t^swz]; rms-over-t computed in-kernel (row sums); A-fragment
// rows = t. 4 waves, 2 blocks/CU (66 KB LDS).
constexpr int XPF = 132;                    // xs row stride (dwords)
__global__ __launch_bounds__(256, 2) void k_projm(
    const float* __restrict__ x, const float* __restrict__ nw,
    const unsigned short* __restrict__ Wcat, const float* __restrict__ bias,
    unsigned short* __restrict__ Lb, unsigned short* __restrict__ XVb)
{
    __shared__ float xs[128 * XPF];         // 67584 B
    __shared__ float sscale[128];
    const int tid = threadIdx.x, lane = tid & 63, wv = tid >> 6;
    const int lr = lane & 31, lhi = lane >> 5;
    const int blk = blockIdx.x;
    const int b = blk >> 10, n = blk & 1023;

    // ---- stage x[b,:,n,:] transposed: xs[c][t ^ swz(c)] ----
    const float* xg = x + ((size_t)(b * Tc) * Nc + n) * 128;
#pragma unroll
    for (int p = 0; p < 8; ++p) {
        int i = p * 256 + tid;
        int t = i >> 4, cg = i & 15;
        const float* src = xg + (size_t)t * NF + cg * 8;
        float4 u0 = *(const float4*)src;
        float4 u1 = *(const float4*)(src + 4);
        int col = t ^ ((cg & 7) << 3);
        float vv[8] = {u0.x, u0.y, u0.z, u0.w, u1.x, u1.y, u1.z, u1.w};
#pragma unroll
        for (int j = 0; j < 8; ++j) xs[(cg * 8 + j) * XPF + col] = vv[j];
    }
    __syncthreads();

    // ---- fused rms1: per c, sum over t (swizzle-oblivious full-row sum) ----
    {
        int c = tid >> 1, half = tid & 1;
        float ss = 0.f;
#pragma unroll
        for (int k = 0; k < 16; ++k) {
            float4 u = *(const float4*)&xs[c * XPF + half * 64 + k * 4];
            ss = fmaf(u.x, u.x, fmaf(u.y, u.y, fmaf(u.z, u.z, fmaf(u.w, u.w, ss))));
        }
        ss += __shfl_xor(ss, 1);
        if (half == 0) sscale[c] = rsqrtf(ss * (1.f / Tc) + EPSc) * nw[c];
    }
    __syncthreads();

    // ---- A-fragments: row = t = wv*32+lr, k = c (col fixed per s, conflict-free) ----
    bf16x8 af[8];
#pragma unroll
    for (int s = 0; s < 8; ++s) {
        const int cbase = s * 16 + lhi * 8;
        const int col = (wv * 32 + lr) ^ (((cbase >> 3) & 7) << 3);
        bf16x8 v;
#pragma unroll
        for (int j = 0; j < 8; ++j) {
            const int c = cbase + j;
            v[j] = (__bf16)(xs[c * XPF + col] * sscale[c]);
        }
        af[s] = v;
    }

#pragma unroll
    for (int ot = 0; ot < 8; ++ot) {
        const unsigned short* pw = Wcat + (size_t)(ot * 32 + lr) * 128 + lhi * 8;
        f32x16 acc = zero16();
#pragma unroll
        for (int s = 0; s < 8; ++s) {
            bf16x8 bw = *(const bf16x8*)(pw + s * 16);
            acc = __builtin_amdgcn_mfma_f32_32x32x16_bf16(af[s], bw, acc, 0, 0, 0);
        }
        const int o = ot * 32 + lr;
        const float bv = bias[o];
        unsigned short* dst = (ot < 4) ? Lb : XVb;
        const int oo = (ot < 4) ? o : o - 128;
#pragma unroll
        for (int r = 0; r < 16; ++r) {
            const int t = wv * 32 + (r & 3) + 8 * (r >> 2) + 4 * lhi;
            dst[((size_t)(b * Tc + t) * Nc + n) * 128 + oo] = f2bu(acc[r] + bv);
        }
    }
}

// ---------------- K3: landmark aggregation + n-softmax stats (parallel, vec loads) ----------------
__global__ __launch_bounds__(256, 4) void k_land(
    const unsigned short* __restrict__ Lb, const unsigned short* __restrict__ XVb,
    float* __restrict__ VL, float* __restrict__ M2, float* __restrict__ S2)
{
    __shared__ float sL [64][34];
    __shared__ float sXV[64][36];
    __shared__ float redm[32][8];
    __shared__ float reds[32][8];
    int tid = threadIdx.x;
    int blk = blockIdx.x;               // bt*4 + h
    int h = blk & 3; int bt = blk >> 2;
    size_t base = (size_t)bt * Nc * 128 + h * 32;
    const int li = tid >> 2, c8 = (tid & 3) * 8;      // load mapping (us8)
    const int r_st = tid & 31, stripe = tid >> 5;     // stats mapping
    const int ti = tid >> 2, sub = tid & 3;           // p1 mapping
    const int r_acc = tid >> 3, d0 = (tid & 7) * 4;   // VL mapping
    float m_st = -1e30f, s_st = 0.f;
    float a0 = 0, a1 = 0, a2 = 0, a3 = 0;
    for (int n0 = 0; n0 < Nc; n0 += 64) {
        {
            size_t g = base + (size_t)(n0 + li) * 128 + c8;
            us8 vL = *(const us8*)(Lb + g);
            us8 vX = *(const us8*)(XVb + g);
#pragma unroll
            for (int j = 0; j < 8; ++j) {
                sL [li][c8 + j] = bu2f(vL[j]);
                sXV[li][c8 + j] = bu2f(vX[j]);
            }
        }
        __syncthreads();
#pragma unroll
        for (int i8 = 0; i8 < 8; ++i8) {
            float v = sL[stripe * 8 + i8][r_st];
            float mn = fmaxf(m_st, v);
            s_st = s_st * __expf(m_st - mn) + __expf(v - mn);
            m_st = mn;
        }
        float e[8];
        float mx = -1e30f;
#pragma unroll
        for (int j = 0; j < 8; ++j) mx = fmaxf(mx, sL[ti][sub * 8 + j]);
        mx = fmaxf(mx, __shfl_xor(mx, 1));
        mx = fmaxf(mx, __shfl_xor(mx, 2));
        float sm = 0.f;
#pragma unroll
        for (int j = 0; j < 8; ++j) { e[j] = __expf(sL[ti][sub * 8 + j] - mx); sm += e[j]; }
        sm += __shfl_xor(sm, 1);
        sm += __shfl_xor(sm, 2);
        float iv = 1.f / sm;
        __syncthreads();                 // all reads of sL done
#pragma unroll
        for (int j = 0; j < 8; ++j) sL[ti][sub * 8 + j] = e[j] * iv;
        __syncthreads();
#pragma unroll 2
        for (int i = 0; i < 64; ++i) {
            float p = sL[i][r_acc];
            float4 v = *(const float4*)&sXV[i][d0];
            a0 = fmaf(p, v.x, a0); a1 = fmaf(p, v.y, a1);
            a2 = fmaf(p, v.z, a2); a3 = fmaf(p, v.w, a3);
        }
        __syncthreads();
    }
    redm[r_st][stripe] = m_st;
    reds[r_st][stripe] = s_st;
    __syncthreads();
    if (tid < 32) {
        float m = -1e30f;
#pragma unroll
        for (int k = 0; k < 8; ++k) m = fmaxf(m, redm[tid][k]);
        float s = 0.f;
#pragma unroll
        for (int k = 0; k < 8; ++k) s += reds[tid][k] * __expf(redm[tid][k] - m);
        M2[blk * 32 + tid] = m;
        S2[blk * 32 + tid] = s;
    }
    *(float4*)&VL[((size_t)blk * 32 + r_acc) * 32 + d0] = make_float4(a0, a1, a2, a3);
}

// ---------------- K4: scatter landmarks + gates + first residual (32 tok/block) ----------------
__global__ __launch_bounds__(256) void k_out1(
    const float* __restrict__ x,
    const unsigned short* __restrict__ Lb, const unsigned short* __restrict__ XVb,
    const float* __restrict__ VL, const float* __restrict__ M2, const float* __restrict__ S2,
    const float* __restrict__ alpha, const float* __restrict__ beta,
    unsigned short* __restrict__ X2b)
{
    __shared__ float sVL[128][32];
    __shared__ float sP[8][128];
    __shared__ float sM[128], sSi[128], sAB[8];
    int tid = threadIdx.x;
    int tk00 = blockIdx.x * 32;          // 32 tokens, all same bt (1024 | 32)
    int bt = tk00 >> 10;
    for (int k = tid; k < 4096; k += 256) sVL[k >> 5][k & 31] = VL[(size_t)bt * 4096 + k];
    if (tid < 128) { sM[tid] = M2[bt * 128 + tid]; sSi[tid] = 1.f / S2[bt * 128 + tid]; }
    if (tid < 8)   sAB[tid] = (tid < 4) ? sigmoidf_(alpha[tid]) : sigmoidf_(beta[tid - 4]);
    __syncthreads();
    const int ti = tid >> 5, quad = tid & 31;
    const int h = quad >> 3, d0 = (quad & 7) * 4;
    const int hr0 = h * 32;
    const int f4 = (tid & 31) * 4;
    const float sa = sAB[h], sb = sAB[4 + h];
    for (int tg = 0; tg < 4; ++tg) {
        const int tk0 = tk00 + tg * 8;
        {
            us4 lv = *(const us4*)&Lb[(size_t)(tk0 + ti) * 128 + f4];
#pragma unroll
            for (int j = 0; j < 4; ++j)
                sP[ti][f4 + j] = __expf(bu2f(lv[j]) - sM[f4 + j]) * sSi[f4 + j];
        }
        __syncthreads();
        float a0 = 0, a1 = 0, a2 = 0, a3 = 0;
#pragma unroll 4
        for (int r = 0; r < 32; ++r) {
            float p = sP[ti][hr0 + r];
            float4 v = *(const float4*)&sVL[hr0 + r][d0];
            a0 = fmaf(p, v.x, a0); a1 = fmaf(p, v.y, a1);
            a2 = fmaf(p, v.z, a2); a3 = fmaf(p, v.w, a3);
        }
        size_t gi = (size_t)(tk0 + ti) * 128 + quad * 4;
        ushort4 xv4 = *(const ushort4*)&XVb[gi];
        float o0 = fmaf(sb, a0, fmaf(sa, bu2f(xv4.x), x[gi + 0]));
        float o1 = fmaf(sb, a1, fmaf(sa, bu2f(xv4.y), x[gi + 1]));
        float o2 = fmaf(sb, a2, fmaf(sa, bu2f(xv4.z), x[gi + 2]));
        float o3 = fmaf(sb, a3, fmaf(sa, bu2f(xv4.w), x[gi + 3]));
        ushort4 pk; pk.x = f2bu(o0); pk.y = f2bu(o1); pk.z = f2bu(o2); pk.w = f2bu(o3);
        *(ushort4*)&X2b[gi] = pk;
        __syncthreads();
    }
}

// ---------------- K6: MFMA FFN + fused rms2 + final residual ----------------
// r6 structure (measured ~234 us): block = (b,n), 4 waves, 2 blocks/CU.
constexpr int XST = 132;                 // xstage row stride (ushorts)
__global__ __launch_bounds__(256, 2) void k_ffn_mfma(
    const unsigned short* __restrict__ X2b, const float* __restrict__ nw,
    const unsigned short* __restrict__ w1b, const float* __restrict__ b1,
    const unsigned short* __restrict__ w2b, const float* __restrict__ b2,
    const unsigned short* __restrict__ w3b, const float* __restrict__ b3,
    float* __restrict__ out)
{
    __shared__ unsigned short smem[18432] __attribute__((aligned(16)));  // 36864 B union
    unsigned short* xstage = smem;           // [128][XST] = 16896 us (prologue)
    unsigned short* gT     = smem;           // [2][128][72] = 18432 us (K-loop)
    __shared__ float sscale[128];

    const int tid  = threadIdx.x;
    const int lane = tid & 63;
    const int wv   = tid >> 6;
    const int lr   = lane & 31;
    const int lhi  = lane >> 5;
    const int blk  = blockIdx.x;
    const int b    = blk >> 10, n = blk & 1023;

    const int mrow = (wv & 1) * 32;     // o-local base (phase B)
    const int fh   = (wv >> 1) * 64;    // f base (phase B)
    const int t0   = wv * 32;           // t-tile base (phase C)

    // ---- stage X2 column-slab into LDS transposed: xstage[f][t ^ swz(f)] ----
    const unsigned short* xg = X2b + ((size_t)(b * Tc) * Nc + n) * 128;
#pragma unroll
    for (int p = 0; p < 8; ++p) {
        int i = p * 256 + tid;
        int t = i >> 4, fg = i & 15;
        us8 v = *(const us8*)(xg + (size_t)t * NF + fg * 8);
        int tt = t ^ ((fg & 7) << 3);
#pragma unroll
        for (int j = 0; j < 8; ++j) xstage[(fg * 8 + j) * XST + tt] = v[j];
    }
    __syncthreads();

    // ---- fused rms2: sum over t of X2^2 per f ----
    {
        int f = tid >> 1, half = tid & 1;
        float ss = 0.f;
#pragma unroll
        for (int kk = 0; kk < 16; ++kk) {
            us4 u = *(const us4*)&xstage[f * XST + half * 64 + kk * 4];
#pragma unroll
            for (int j = 0; j < 4; ++j) { float v = bu2f(u[j]); ss = fmaf(v, v, ss); }
        }
        ss += __shfl_xor(ss, 1);
        if (half == 0) sscale[f] = rsqrtf(ss * (1.f / Tc) + EPSc) * nw[f];
    }
    __syncthreads();

    // ---- build XN B-fragments from LDS (2 f-tiles, 64 VGPR) ----
    bf16x8 xnf[2][8];
#pragma unroll
    for (int ft = 0; ft < 2; ++ft) {
        const int f = fh + ft * 32 + lr;
        const int swz = ((f >> 3) & 7) << 3;
        const float scale = sscale[f];
#pragma unroll
        for (int s = 0; s < 8; ++s) {
            int tb = (s * 16 + lhi * 8) ^ swz;
            us4 u0 = *(const us4*)&xstage[f * XST + tb];
            us4 u1 = *(const us4*)&xstage[f * XST + tb + 4];
            bf16x8 v;
#pragma unroll
            for (int j = 0; j < 4; ++j) {
                v[j]     = (__bf16)(bu2f(u0[j]) * scale);
                v[j + 4] = (__bf16)(bu2f(u1[j]) * scale);
            }
            xnf[ft][s] = v;
        }
    }

    // ---- oacc init: residual + b3, raw X2 from xstage ----
    f32x16 oacc[4];
#pragma unroll
    for (int c = 0; c < 4; ++c) {
        const int f = c * 32 + lr;
        const int swz = ((f >> 3) & 7) << 3;
#pragma unroll
        for (int q = 0; q < 4; ++q) {
            const int tb = t0 + 8 * q + 4 * lhi;
            us4 u = *(const us4*)&xstage[f * XST + (tb ^ swz)];
#pragma unroll
            for (int e = 0; e < 4; ++e)
                oacc[c][q * 4 + e] = bu2f(u[e]) + b3[tb + e];
        }
    }
    __syncthreads();    // xstage dead; gT may now be written

    const unsigned short* w1r = w1b + (size_t)(mrow + lr) * 128 + lhi * 8;
    const unsigned short* w2r = w2b + (size_t)(mrow + lr) * 128 + lhi * 8;
    const unsigned short* w3r = w3b + (size_t)(t0 + lr) * 512 + lhi * 8;

    int d = 0;
    for (int oc = 0; oc < 512; oc += 64) {
        // prefetch w3 fragments for this chunk (consumed after the barrier)
        bf16x8 a3[4];
        const unsigned short* pw3 = w3r + oc;
#pragma unroll
        for (int s = 0; s < 4; ++s) a3[s] = *(const bf16x8*)(pw3 + s * 16);

        // ---------- phase B: H1/H2 for this o-chunk (4 independent chains) ----------
        f32x16 h1a = zero16(), h1b = zero16(), h2a = zero16(), h2b = zero16();
        const unsigned short* pw1 = w1r + (size_t)oc * 128;
        const unsigned short* pw2 = w2r + (size_t)oc * 128;
#pragma unroll
        for (int s = 0; s < 8; ++s) {
            bf16x8 a1 = *(const bf16x8*)(pw1 + s * 16);
            bf16x8 a2 = *(const bf16x8*)(pw2 + s * 16);
            h1a = __builtin_amdgcn_mfma_f32_32x32x16_bf16(a1, xnf[0][s], h1a, 0, 0, 0);
            h1b = __builtin_amdgcn_mfma_f32_32x32x16_bf16(a1, xnf[1][s], h1b, 0, 0, 0);
            h2a = __builtin_amdgcn_mfma_f32_32x32x16_bf16(a2, xnf[0][s], h2a, 0, 0, 0);
            h2b = __builtin_amdgcn_mfma_f32_32x32x16_bf16(a2, xnf[1][s], h2b, 0, 0, 0);
        }
        // g = silu(h1 + b1) * (h2 + b2) -> gT[d]
        unsigned short* gTd = gT + d * 9216;
#pragma unroll
        for (int ft = 0; ft < 2; ++ft) {
            const int fcol = fh + ft * 32 + lr;
#pragma unroll
            for (int q = 0; q < 4; ++q) {
                ushort4 pk;
#pragma unroll
                for (int e = 0; e < 4; ++e) {
                    const int r = q * 4 + e;
                    const int orow = oc + mrow + e + 8 * q + 4 * lhi;
                    float z   = (ft ? h1b[r] : h1a[r]) + b1[orow];
                    float h2v = (ft ? h2b[r] : h2a[r]) + b2[orow];
                    float g   = z * sigmoidf_(z) * h2v;
                    unsigned short gb = f2bu(g);
                    if (e == 0) pk.x = gb; else if (e == 1) pk.y = gb;
                    else if (e == 2) pk.z = gb; else pk.w = gb;
                }
                const int o_l = mrow + 8 * q + 4 * lhi;
                *(ushort4*)&gTd[fcol * 72 + o_l] = pk;
            }
        }
        __syncthreads();
        // ---------- phase C: OUT += W3[:, oc..oc+63] * G ----------
#pragma unroll
        for (int s = 0; s < 4; ++s) {
#pragma unroll
            for (int c = 0; c < 4; ++c) {
                bf16x8 bg = *(const bf16x8*)&gTd[(c * 32 + lr) * 72 + s * 16 + lhi * 8];
                oacc[c] = __builtin_amdgcn_mfma_f32_32x32x16_bf16(a3[s], bg, oacc[c], 0, 0, 0);
            }
        }
        d ^= 1;   // next phase B writes the other buffer; no second barrier needed
    }

    // ---------- epilogue: out = oacc (residual+b3 already folded in) ----------
#pragma unroll
    for (int r = 0; r < 16; ++r) {
        const int t = t0 + (r & 3) + 8 * (r >> 2) + 4 * lhi;
        const size_t rowbase = ((size_t)(b * Tc + t) * Nc + n) * 128;
#pragma unroll
        for (int c = 0; c < 4; ++c) {
            out[rowbase + c * 32 + lr] = oacc[c][r];
        }
    }
}

extern "C" void kernel_launch(void* const* d_in, const int* in_sizes, int n_in,
                              void* d_out, int out_size, void* d_ws, size_t ws_size,
                              hipStream_t stream) {
    const float* x      = (const float*)d_in[0];
    const float* norm_w = (const float*)d_in[1];
    const float* q_w    = (const float*)d_in[2];
    const float* q_b    = (const float*)d_in[3];
    const float* key_p  = (const float*)d_in[4];
    const float* v_w    = (const float*)d_in[5];
    const float* v_b    = (const float*)d_in[6];
    const float* alpha  = (const float*)d_in[7];
    const float* beta   = (const float*)d_in[8];
    const float* w1     = (const float*)d_in[9];
    const float* b1     = (const float*)d_in[10];
    const float* w2     = (const float*)d_in[11];
    const float* b2     = (const float*)d_in[12];
    const float* w3     = (const float*)d_in[13];
    const float* b3     = (const float*)d_in[14];
    float* out = (float*)d_out;

    char* ws = (char*)d_ws;
    float* inv1 = (float*)ws;                                    // 262144 f (spare now)
    float* inv2 = inv1 + (size_t)Bc * NF;                        // 262144 f (holds wbf)
    float* VLp  = inv2 + (size_t)Bc * NF;                        // 1048576 f
    float* M2p  = VLp + (size_t)Bc * Tc * Hc * Rc * Dc;          // 32768 f
    float* S2p  = M2p + (size_t)Bc * Tc * Hc * Rc;               // 32768 f
    unsigned short* Lb  = (unsigned short*)(S2p + (size_t)Bc * Tc * Hc * Rc);
    unsigned short* XVb = Lb  + (size_t)TOK * 128;
    unsigned short* X2b = XVb + (size_t)TOK * 128;               // total ~198.3 MiB

    // Wcat (256x128 bf16) + bias (256 f) alias the VLp region (VL written later by k_land)
    unsigned short* Wcat = (unsigned short*)VLp;                 // 32768 us
    float* bias256 = VLp + 16384;

    // bf16 weight copies live in the spare inv2 region (384 KB < 1 MB)
    unsigned short* w1bf = (unsigned short*)inv2;
    unsigned short* w2bf = w1bf + 65536;
    unsigned short* w3bf = w1bf + 131072;

    k_prep    <<<836,           256, 0, stream>>>(q_w, q_b, key_p, v_b, v_w,
                                                  Wcat, bias256, w1, w2, w3, w1bf);
    k_projm   <<<Bc * Nc,       256, 0, stream>>>(x, norm_w, Wcat, bias256, Lb, XVb);
    k_land    <<<Bc * Tc * Hc,  256, 0, stream>>>(Lb, XVb, VLp, M2p, S2p);
    k_out1    <<<TOK / 32,      256, 0, stream>>>(x, Lb, XVb, VLp, M2p, S2p, alpha, beta, X2b);
    k_ffn_mfma<<<Bc * Nc,       256, 0, stream>>>(X2b, norm_w, w1bf, b1, w2bf, b2, w3bf, b3, out);
}